// Round 3
// baseline (764.220 us; speedup 1.0000x reference)
//
#include <hip/hip_runtime.h>
#include <cstdint>
#include <cstddef>

typedef __bf16 bf16;
typedef __bf16 bf16x4 __attribute__((ext_vector_type(4)));
typedef __bf16 bf16x8 __attribute__((ext_vector_type(8)));
typedef float  f32x4  __attribute__((ext_vector_type(4)));
typedef unsigned int uint;

#define EPS 1e-5f

// ---------------------------------------------------------------------------
// fused: x -> bf16 copy + per-(b,d) partial sums for mean/std. grid (64,16)
// ---------------------------------------------------------------------------
__global__ __launch_bounds__(256)
void convert_stats(const float* __restrict__ x, bf16* __restrict__ xb,
                   float* __restrict__ p1, float* __restrict__ p2)
{
    const int b = blockIdx.x, lc = blockIdx.y, d = threadIdx.x;
    const size_t base = ((size_t)b * 1024 + lc * 64) * 256;
    float s = 0.f, s2 = 0.f;
    #pragma unroll 4
    for (int l = 0; l < 64; l++) {
        float v = x[base + (size_t)l * 256 + d];
        xb[base + (size_t)l * 256 + d] = (bf16)v;
        s += v; s2 += v * v;
    }
    p1[((size_t)lc * 64 + b) * 256 + d] = s;
    p2[((size_t)lc * 64 + b) * 256 + d] = s2;
}

// ---------------------------------------------------------------------------
// all weight prep in ONE dispatch: 4 transposes + 4 scale/bias. 3592 blocks.
// ---------------------------------------------------------------------------
__global__ void prep_all(
    const float* __restrict__ W1, const float* __restrict__ W2,
    const float* __restrict__ W3, const float* __restrict__ W4,
    bf16* __restrict__ t1, bf16* __restrict__ t2,
    bf16* __restrict__ t3, bf16* __restrict__ t4,
    const float* b1, const float* g1, const float* be1, const float* m1, const float* v1,
    const float* b2, const float* g2, const float* be2, const float* m2, const float* v2,
    const float* b3, const float* g3, const float* be3, const float* m3, const float* v3,
    const float* b4, const float* g4, const float* be4, const float* m4, const float* v4,
    float* __restrict__ sb)
{
    const int bid = blockIdx.x, tid = threadIdx.x;
    if (bid < 512) {                       // W1: 512x256 (Wt[n][k])
        int idx = bid * 256 + tid;
        int n = idx >> 8, k = idx & 255;
        t1[idx] = (bf16)W1[k * 512 + n];
    } else if (bid < 3584) {               // W2/W3/W4: 512x512 each
        int r = bid - 512;
        int which = r >> 10;               // 1024 blocks each
        int idx = (r & 1023) * 256 + tid;
        int n = idx >> 9, k = idx & 511;
        const float* W = which == 0 ? W2 : (which == 1 ? W3 : W4);
        bf16* Wt       = which == 0 ? t2 : (which == 1 ? t3 : t4);
        Wt[idx] = (bf16)W[k * 512 + n];
    } else {                               // scale/bias: 8 blocks
        int r = bid - 3584;
        int lay = r >> 1;
        int j = (r & 1) * 256 + tid;
        const float *b, *g, *be, *m, *v;
        switch (lay) {
            case 0: b=b1; g=g1; be=be1; m=m1; v=v1; break;
            case 1: b=b2; g=g2; be=be2; m=m2; v=v2; break;
            case 2: b=b3; g=g3; be=be3; m=m3; v=v3; break;
            default:b=b4; g=g4; be=be4; m=m4; v=v4; break;
        }
        float sj = g[j] * rsqrtf(v[j] + EPS);
        sb[lay * 1024 + j]       = sj;
        sb[lay * 1024 + 512 + j] = (b[j] - m[j]) * sj + be[j];
    }
}

// ---------------------------------------------------------------------------
// GEMM: C[M,512] = relu( (A[M,K] @ Wt[512,K]^T) * s + t ), bf16 out
// 128x256 tile, BK=32, 512 threads = 8 waves (2m x 4n), wave tile 64x64.
//
// REGISTER-DIRECT: no LDS, no barriers. Operands here are cache-sized
// (B panel 256KB = L2-resident; A K-slice 8KB with 4-way intra-block reuse
// = L1-resident), so the LDS round-trip + 2-barriers-per-K-step convoy
// bought nothing (r1/r2: 68us flat, MfmaUtil 20%). Each wave loads its MFMA
// fragments straight global->reg: the fragment layout per lane
// (row = m0+wm*64+i*16+l16, cols k0+quad*8..+7) is a dense 16B load at a
// per-lane address -> one global_load_dwordx4 per fragment. 2-tile-deep
// register double buffer (named sets, constant-indexed; rule #20 safe);
// per-wave vmcnt FIFO + 8 waves/CU TLP hide L2 latency. Compiler inserts
// fine-grained waitcnts (it is good at this, m97); no inline asm needed.
// ---------------------------------------------------------------------------
template<int K>
__global__ __launch_bounds__(512, 2)
void gemm_bt(const bf16* __restrict__ A, const bf16* __restrict__ Bt,
             const float* __restrict__ sc, const float* __restrict__ bi,
             bf16* __restrict__ C)
{
    constexpr int NT = K / 32;            // K-tiles of 32 (even: 8 or 16)

    const int tid  = threadIdx.x;
    const int lane = tid & 63;
    const int wid  = tid >> 6;            // 0..7
    const int wm   = wid >> 2;            // 0..1 (m half)
    const int wn   = wid & 3;             // 0..3 (n quarter)
    const size_t m0 = (size_t)blockIdx.x * 128;
    const int    n0 = blockIdx.y * 256;

    const int quad = lane >> 4;
    const int l16  = lane & 15;

    // per-lane fragment base pointers (advance by +32 elems per K-tile)
    const bf16* Ap[4];
    const bf16* Bp[4];
    #pragma unroll
    for (int i = 0; i < 4; i++)
        Ap[i] = &A[(m0 + wm * 64 + i * 16 + l16) * K + quad * 8];
    #pragma unroll
    for (int j = 0; j < 4; j++)
        Bp[j] = &Bt[(size_t)(n0 + wn * 64 + j * 16 + l16) * K + quad * 8];

    bf16x8 a0[4], b0[4], a1[4], b1[4];
    #pragma unroll
    for (int i = 0; i < 4; i++) {
        a0[i] = *(const bf16x8*)(Ap[i]);
        b0[i] = *(const bf16x8*)(Bp[i]);
    }
    #pragma unroll
    for (int i = 0; i < 4; i++) {
        a1[i] = *(const bf16x8*)(Ap[i] + 32);
        b1[i] = *(const bf16x8*)(Bp[i] + 32);
    }

    f32x4 acc[4][4] = {};

    for (int t = 0; t < NT; t += 2) {
        #pragma unroll
        for (int i = 0; i < 4; i++)
            #pragma unroll
            for (int j = 0; j < 4; j++)
                acc[i][j] = __builtin_amdgcn_mfma_f32_16x16x32_bf16(a0[i], b0[j], acc[i][j], 0, 0, 0);
        if (t + 2 < NT) {
            const int ko = (t + 2) * 32;
            #pragma unroll
            for (int i = 0; i < 4; i++) {
                a0[i] = *(const bf16x8*)(Ap[i] + ko);
                b0[i] = *(const bf16x8*)(Bp[i] + ko);
            }
        }
        #pragma unroll
        for (int i = 0; i < 4; i++)
            #pragma unroll
            for (int j = 0; j < 4; j++)
                acc[i][j] = __builtin_amdgcn_mfma_f32_16x16x32_bf16(a1[i], b1[j], acc[i][j], 0, 0, 0);
        if (t + 3 < NT) {
            const int ko = (t + 3) * 32;
            #pragma unroll
            for (int i = 0; i < 4; i++) {
                a1[i] = *(const bf16x8*)(Ap[i] + ko);
                b1[i] = *(const bf16x8*)(Bp[i] + ko);
            }
        }
    }

    // epilogue: C/D layout col = lane&15, row = quad*4 + r  [m89/m91 verified]
    #pragma unroll
    for (int j = 0; j < 4; j++) {
        const int col = n0 + wn * 64 + j * 16 + l16;
        const float s = sc[col], t = bi[col];
        #pragma unroll
        for (int i = 0; i < 4; i++) {
            const size_t rowb = m0 + wm * 64 + i * 16 + quad * 4;
            #pragma unroll
            for (int r = 0; r < 4; r++) {
                float v = acc[i][j][r] * s + t;
                v = v > 0.f ? v : 0.f;
                C[(rowb + r) * 512 + col] = (bf16)v;
            }
        }
    }
}

// ---------------------------------------------------------------------------
// A[N,8] = h4[N,512](bf16) @ Wa[512,8](f32)
// ---------------------------------------------------------------------------
__global__ __launch_bounds__(256)
void compute_A(const bf16* __restrict__ h, const float* __restrict__ Wa,
               float* __restrict__ A)
{
    __shared__ float WaL[512 * 8];
    const int tid = threadIdx.x;
    for (int i = tid; i < 4096; i += 256) WaL[i] = Wa[i];
    __syncthreads();
    const size_t row = (size_t)blockIdx.x * 32 + (tid >> 3);
    const int r = tid & 7;
    const bf16* hp = h + row * 512;
    float acc0 = 0.f, acc1 = 0.f;
    #pragma unroll 4
    for (int k8 = 0; k8 < 64; k8 += 2) {
        bf16x8 h0 = *(const bf16x8*)&hp[k8 * 8];
        bf16x8 h1 = *(const bf16x8*)&hp[k8 * 8 + 8];
        #pragma unroll
        for (int j = 0; j < 8; j++) {
            acc0 += (float)h0[j] * WaL[(k8 * 8 + j) * 8 + r];
            acc1 += (float)h1[j] * WaL[(k8 * 8 + 8 + j) * 8 + r];
        }
    }
    A[row * 8 + r] = acc0 + acc1;
}

// ---------------------------------------------------------------------------
// per-segment softmax over L (8 cols) + penalty. 1024 threads.
// ---------------------------------------------------------------------------
__global__ __launch_bounds__(1024)
void seg_softmax(const float* __restrict__ A, float* __restrict__ Asg,
                 float* __restrict__ pen)
{
    __shared__ float AsL[8192];
    __shared__ float red[1024];
    __shared__ float amax[8], asum[8];
    const int b = blockIdx.x, tid = threadIdx.x;
    const float* Ab = A + (size_t)b * 8192;
    for (int i = tid * 4; i < 8192; i += 4096)
        *(float4*)&AsL[i] = *(const float4*)&Ab[i];
    __syncthreads();
    const int r = tid & 7, chunk = tid >> 3;      // 128 chunks x 8 rows
    float pm = -1e30f;
    for (int l = chunk * 8; l < chunk * 8 + 8; l++) pm = fmaxf(pm, AsL[l * 8 + r]);
    red[tid] = pm;
    __syncthreads();
    if (tid < 512) red[tid] = fmaxf(red[tid], red[tid + 512]); __syncthreads();
    if (tid < 256) red[tid] = fmaxf(red[tid], red[tid + 256]); __syncthreads();
    if (tid < 128) red[tid] = fmaxf(red[tid], red[tid + 128]); __syncthreads();
    if (tid <  64) red[tid] = fmaxf(red[tid], red[tid +  64]); __syncthreads();
    if (tid <  32) red[tid] = fmaxf(red[tid], red[tid +  32]); __syncthreads();
    if (tid <  16) red[tid] = fmaxf(red[tid], red[tid +  16]); __syncthreads();
    if (tid <   8) amax[tid] = fmaxf(red[tid], red[tid + 8]);  __syncthreads();
    const float mr = amax[r];
    float ps = 0.f;
    for (int l = chunk * 8; l < chunk * 8 + 8; l++) {
        float e = expf(AsL[l * 8 + r] - mr);
        AsL[l * 8 + r] = e;
        ps += e;
    }
    red[tid] = ps;
    __syncthreads();
    if (tid < 512) red[tid] += red[tid + 512]; __syncthreads();
    if (tid < 256) red[tid] += red[tid + 256]; __syncthreads();
    if (tid < 128) red[tid] += red[tid + 128]; __syncthreads();
    if (tid <  64) red[tid] += red[tid +  64]; __syncthreads();
    if (tid <  32) red[tid] += red[tid +  32]; __syncthreads();
    if (tid <  16) red[tid] += red[tid +  16]; __syncthreads();
    if (tid <   8) asum[tid] = red[tid] + red[tid + 8];        __syncthreads();
    const float inv = 1.f / asum[r];
    for (int l = chunk * 8; l < chunk * 8 + 8; l++) AsL[l * 8 + r] *= inv;
    __syncthreads();
    for (int i = tid * 4; i < 8192; i += 4096)
        *(float4*)&Asg[(size_t)b * 8192 + i] = *(const float4*)&AsL[i];
    __syncthreads();
    // penalty: 64 (rr,ss) pairs x 16 l-chunks of 64
    {
        const int p = tid & 63, ch = tid >> 6;
        const int rr = p >> 3, ss = p & 7;
        float dot = 0.f;
        for (int l = ch * 64; l < ch * 64 + 64; l++)
            dot += AsL[l * 8 + rr] * AsL[l * 8 + ss];
        red[tid] = dot;
    }
    __syncthreads();
    if (tid < 512) red[tid] += red[tid + 512]; __syncthreads();
    if (tid < 256) red[tid] += red[tid + 256]; __syncthreads();
    if (tid < 128) red[tid] += red[tid + 128]; __syncthreads();
    if (tid < 64) {
        float d = red[tid] + red[tid + 64] - 1.f;
        red[tid] = d * d;
    }
    __syncthreads();
    if (tid == 0) {
        float s = 0.f;
        for (int i = 0; i < 64; i++) s += red[i];
        atomicAdd(pen, s);
    }
}

// ---------------------------------------------------------------------------
// pooled partials: grid (64, 4 col-chunks, 8 l-chunks of 128)
// ---------------------------------------------------------------------------
__global__ __launch_bounds__(256)
void pooled_k(const float* __restrict__ Asg, const bf16* __restrict__ h,
              float* __restrict__ pp)
{
    const int b = blockIdx.x;
    const int cc0 = blockIdx.y * 128;
    const int lc = blockIdx.z;
    const int tid = threadIdx.x;
    const int c = tid & 127, rg = tid >> 7;
    float a0 = 0, a1 = 0, a2 = 0, a3 = 0;
    const float* Asb = Asg + (size_t)b * 8192 + (size_t)lc * 128 * 8 + rg * 4;
    const bf16* hb = h + ((size_t)b * 1024 + lc * 128) * 512 + cc0 + c;
    #pragma unroll 4
    for (int l = 0; l < 128; l++) {
        float4 a = *(const float4*)&Asb[(size_t)l * 8];
        float hv = (float)hb[(size_t)l * 512];
        a0 += a.x * hv; a1 += a.y * hv; a2 += a.z * hv; a3 += a.w * hv;
    }
    float* pb = pp + ((size_t)lc * 64 + b) * 4096 + (rg * 4) * 512 + cc0 + c;
    pb[0] = a0; pb[512] = a1; pb[1024] = a2; pb[1536] = a3;
}

// ---------------------------------------------------------------------------
// head pass 1: z[b][c] += feat-chunk @ Wo1-slice. grid (64, 9)
// kc==8 computes mean/std inline from the convert_stats partials.
// ---------------------------------------------------------------------------
__global__ __launch_bounds__(128)
void head1(const float* __restrict__ pp, const float* __restrict__ p1,
           const float* __restrict__ p2, const float* __restrict__ Wo1,
           float* __restrict__ zbuf)
{
    __shared__ float f[512];
    const int b = blockIdx.x, kc = blockIdx.y, tid = threadIdx.x;
    if (kc < 8) {
        for (int j = tid; j < 512; j += 128) {
            const size_t i = (size_t)kc * 512 + j;
            float s = 0.f;
            #pragma unroll
            for (int lc = 0; lc < 8; lc++)
                s += pp[((size_t)lc * 64 + b) * 4096 + i];
            f[j] = s;
        }
    } else {
        for (int j = tid; j < 256; j += 128) {
            float s = 0.f, s2 = 0.f;
            #pragma unroll
            for (int lc = 0; lc < 16; lc++) {
                s  += p1[((size_t)lc * 64 + b) * 256 + j];
                s2 += p2[((size_t)lc * 64 + b) * 256 + j];
            }
            float m = s * (1.f / 1024.f);
            float var = (s2 - s * m) * (1.f / 1023.f);
            f[j]       = m;
            f[256 + j] = sqrtf(fmaxf(var, 0.f));
        }
    }
    __syncthreads();
    const float* Wp = Wo1 + (size_t)kc * 512 * 128 + tid;
    float z = 0.f;
    #pragma unroll 8
    for (int j = 0; j < 512; j++) z += f[j] * Wp[(size_t)j * 128];
    atomicAdd(&zbuf[b * 128 + tid], z);
}

// ---------------------------------------------------------------------------
// head pass 2: BN+relu -> @ Wo2 -> log_softmax; b==0 writes penalty
// ---------------------------------------------------------------------------
__global__ __launch_bounds__(128)
void head2(const float* __restrict__ zbuf, const float* __restrict__ bo1,
           const float* __restrict__ go, const float* __restrict__ beo,
           const float* __restrict__ mo, const float* __restrict__ vo,
           const float* __restrict__ Wo2, const float* __restrict__ bo2,
           const float* __restrict__ pen, float* __restrict__ out)
{
    __shared__ float o[128];
    __shared__ float lg[4];
    const int b = blockIdx.x, tid = threadIdx.x;
    float z = zbuf[b * 128 + tid];
    float s = go[tid] * rsqrtf(vo[tid] + EPS);
    float t = (bo1[tid] - mo[tid]) * s + beo[tid];
    float ov = z * s + t;
    o[tid] = ov > 0.f ? ov : 0.f;
    __syncthreads();
    if (tid < 4) {
        float acc = bo2[tid];
        for (int j = 0; j < 128; j++) acc += o[j] * Wo2[j * 4 + tid];
        lg[tid] = acc;
    }
    __syncthreads();
    if (tid == 0) {
        float m = fmaxf(fmaxf(lg[0], lg[1]), fmaxf(lg[2], lg[3]));
        float sum = 0.f;
        for (int k = 0; k < 4; k++) sum += expf(lg[k] - m);
        float lse = m + logf(sum);
        for (int k = 0; k < 4; k++) out[b * 4 + k] = lg[k] - lse;
        if (b == 0) out[256] = pen[0];
    }
}

// ---------------------------------------------------------------------------
extern "C" void kernel_launch(void* const* d_in, const int* in_sizes, int n_in,
                              void* d_out, int out_size, void* d_ws, size_t ws_size,
                              hipStream_t stream)
{
    const float* x   = (const float*)d_in[0];
    const float* Wa  = (const float*)d_in[2];
    const float* Wo1 = (const float*)d_in[3];
    const float* bo1 = (const float*)d_in[4];
    const float* go  = (const float*)d_in[5];
    const float* beo = (const float*)d_in[6];
    const float* mo  = (const float*)d_in[7];
    const float* vo  = (const float*)d_in[8];
    const float* Wo2 = (const float*)d_in[9];
    const float* bo2 = (const float*)d_in[10];
    const float *W[4], *bb[4], *gg[4], *be[4], *mm[4], *vv[4];
    for (int l = 0; l < 4; l++) {
        W[l]  = (const float*)d_in[11 + 6 * l + 0];
        bb[l] = (const float*)d_in[11 + 6 * l + 1];
        gg[l] = (const float*)d_in[11 + 6 * l + 2];
        be[l] = (const float*)d_in[11 + 6 * l + 3];
        mm[l] = (const float*)d_in[11 + 6 * l + 4];
        vv[l] = (const float*)d_in[11 + 6 * l + 5];
    }

    char* w = (char*)d_ws;
    bf16* xb  = (bf16*)w;  w += (size_t)65536 * 256 * 2;   // 32 MB
    bf16* hA  = (bf16*)w;  w += (size_t)65536 * 512 * 2;   // 64 MB
    bf16* hB  = (bf16*)w;  w += (size_t)65536 * 512 * 2;   // 64 MB
    bf16* w1t = (bf16*)w;  w += (size_t)512 * 256 * 2;
    bf16* w2t = (bf16*)w;  w += (size_t)512 * 512 * 2;
    bf16* w3t = (bf16*)w;  w += (size_t)512 * 512 * 2;
    bf16* w4t = (bf16*)w;  w += (size_t)512 * 512 * 2;
    float* sb = (float*)w; w += (size_t)4 * 1024 * 4;      // [layer][s|t][512]
    float* Ab = (float*)w; w += (size_t)65536 * 8 * 4;
    float* As = (float*)w; w += (size_t)65536 * 8 * 4;
    float* pp = (float*)w; w += (size_t)8 * 64 * 4096 * 4; // pooled partials
    float* p1 = (float*)w; w += (size_t)16 * 64 * 256 * 4;
    float* p2 = (float*)w; w += (size_t)16 * 64 * 256 * 4;
    float* zbuf = (float*)w; w += (size_t)64 * 128 * 4;
    float* pen = (float*)w;

    hipMemsetAsync(zbuf, 0, (64 * 128 + 1) * sizeof(float), stream); // zbuf + pen

    convert_stats<<<dim3(64, 16), 256, 0, stream>>>(x, xb, p1, p2);
    prep_all<<<3592, 256, 0, stream>>>(
        W[0], W[1], W[2], W[3], w1t, w2t, w3t, w4t,
        bb[0], gg[0], be[0], mm[0], vv[0],
        bb[1], gg[1], be[1], mm[1], vv[1],
        bb[2], gg[2], be[2], mm[2], vv[2],
        bb[3], gg[3], be[3], mm[3], vv[3], sb);

    gemm_bt<256><<<dim3(512, 2), 512, 0, stream>>>(xb, w1t, sb + 0,    sb + 512,  hA);
    gemm_bt<512><<<dim3(512, 2), 512, 0, stream>>>(hA, w2t, sb + 1024, sb + 1536, hB);
    gemm_bt<512><<<dim3(512, 2), 512, 0, stream>>>(hB, w3t, sb + 2048, sb + 2560, hA);
    gemm_bt<512><<<dim3(512, 2), 512, 0, stream>>>(hA, w4t, sb + 3072, sb + 3584, hB);

    compute_A<<<2048, 256, 0, stream>>>(hB, Wa, Ab);
    seg_softmax<<<64, 1024, 0, stream>>>(Ab, As, pen);
    pooled_k<<<dim3(64, 4, 8), 256, 0, stream>>>(As, hB, pp);
    head1<<<dim3(64, 9), 128, 0, stream>>>(pp, p1, p2, Wo1, zbuf);
    head2<<<64, 128, 0, stream>>>(zbuf, bo1, go, beo, mo, vo, Wo2, bo2,
                                  pen, (float*)d_out);
}

// Round 4
// 517.934 us; speedup vs baseline: 1.4755x; 1.4755x over previous
//
#include <hip/hip_runtime.h>
#include <cstdint>
#include <cstddef>

typedef __bf16 bf16;
typedef __bf16 bf16x4 __attribute__((ext_vector_type(4)));
typedef __bf16 bf16x8 __attribute__((ext_vector_type(8)));
typedef float  f32x4  __attribute__((ext_vector_type(4)));
typedef unsigned int uint;

#define EPS 1e-5f

// ---------------------------------------------------------------------------
// async global->LDS, 16B per lane. LDS dest is wave-uniform base + lane*16.
// ---------------------------------------------------------------------------
__device__ __forceinline__ void load_lds16(const void* g, void* l) {
    typedef __attribute__((address_space(1))) void gvoid;
    typedef __attribute__((address_space(3))) void lvoid;
    gvoid* gp = (gvoid*)(unsigned long long)(uintptr_t)g;
    lvoid* lp = (lvoid*)(unsigned int)(uintptr_t)l;
    __builtin_amdgcn_global_load_lds(gp, lp, 16, 0, 0);
}

// ---------------------------------------------------------------------------
// fused: x -> bf16 copy + per-(b,d) partial sums for mean/std. grid (64,16)
// ---------------------------------------------------------------------------
__global__ __launch_bounds__(256)
void convert_stats(const float* __restrict__ x, bf16* __restrict__ xb,
                   float* __restrict__ p1, float* __restrict__ p2)
{
    const int b = blockIdx.x, lc = blockIdx.y, d = threadIdx.x;
    const size_t base = ((size_t)b * 1024 + lc * 64) * 256;
    float s = 0.f, s2 = 0.f;
    #pragma unroll 4
    for (int l = 0; l < 64; l++) {
        float v = x[base + (size_t)l * 256 + d];
        xb[base + (size_t)l * 256 + d] = (bf16)v;
        s += v; s2 += v * v;
    }
    p1[((size_t)lc * 64 + b) * 256 + d] = s;
    p2[((size_t)lc * 64 + b) * 256 + d] = s2;
}

// ---------------------------------------------------------------------------
// all weight prep in ONE dispatch: 4 transposes + 4 scale/bias. 3592 blocks.
// ---------------------------------------------------------------------------
__global__ void prep_all(
    const float* __restrict__ W1, const float* __restrict__ W2,
    const float* __restrict__ W3, const float* __restrict__ W4,
    bf16* __restrict__ t1, bf16* __restrict__ t2,
    bf16* __restrict__ t3, bf16* __restrict__ t4,
    const float* b1, const float* g1, const float* be1, const float* m1, const float* v1,
    const float* b2, const float* g2, const float* be2, const float* m2, const float* v2,
    const float* b3, const float* g3, const float* be3, const float* m3, const float* v3,
    const float* b4, const float* g4, const float* be4, const float* m4, const float* v4,
    float* __restrict__ sb)
{
    const int bid = blockIdx.x, tid = threadIdx.x;
    if (bid < 512) {                       // W1: 512x256 (Wt[n][k])
        int idx = bid * 256 + tid;
        int n = idx >> 8, k = idx & 255;
        t1[idx] = (bf16)W1[k * 512 + n];
    } else if (bid < 3584) {               // W2/W3/W4: 512x512 each
        int r = bid - 512;
        int which = r >> 10;               // 1024 blocks each
        int idx = (r & 1023) * 256 + tid;
        int n = idx >> 9, k = idx & 511;
        const float* W = which == 0 ? W2 : (which == 1 ? W3 : W4);
        bf16* Wt       = which == 0 ? t2 : (which == 1 ? t3 : t4);
        Wt[idx] = (bf16)W[k * 512 + n];
    } else {                               // scale/bias: 8 blocks
        int r = bid - 3584;
        int lay = r >> 1;
        int j = (r & 1) * 256 + tid;
        const float *b, *g, *be, *m, *v;
        switch (lay) {
            case 0: b=b1; g=g1; be=be1; m=m1; v=v1; break;
            case 1: b=b2; g=g2; be=be2; m=m2; v=v2; break;
            case 2: b=b3; g=g3; be=be3; m=m3; v=v3; break;
            default:b=b4; g=g4; be=be4; m=m4; v=v4; break;
        }
        float sj = g[j] * rsqrtf(v[j] + EPS);
        sb[lay * 1024 + j]       = sj;
        sb[lay * 1024 + 512 + j] = (b[j] - m[j]) * sj + be[j];
    }
}

// ---------------------------------------------------------------------------
// GEMM: C[M,512] = relu( (A[M,K] @ Wt[512,K]^T) * s + t ), bf16 out
//
// 8-phase-style schedule (T2+T3+T4+T5), 256x256 tile, BK=64, 512 thr =
// 8 waves (2m x 4n), wave tile 128x64, acc[8][4] f32x4. LDS = 2 x 64KB dbuf.
// Grid 512 blocks = 1 block/CU, 2 rounds; XCD-swizzled block ids.
//
// Per K-tile t: 4 phases. Phase p: {issue 1 staging chunk of tile t+1 ->
// counted vmcnt -> raw s_barrier -> ds_read one frag quadrant ->
// 16 MFMA (setprio 1) -> sched_barrier(0)}. Chunk issue order A0,B0,B1,A1
// equals phase consumption order, so steady-state vmcnt(6) leaves the 3
// youngest chunks (6 loads) in flight across barriers -- loads never drain
// to 0 in the main loop (T4). Last tile drains 4/2/0.
//
// LDS is subtiled in 1KB fragment blocks [blk][lane][8 bf16]: every
// ds_read_b128 reads 64 consecutive 16B -> conflict-free; global_load_lds
// writes linearly (wave base + lane*16) and the per-lane GLOBAL source is
// permuted to match (rule 21).
//   A region (32KB/buf): ih*8192 + (wmblk*8 + iloc*2 + ks)*512 + lane*8
//   B region (32KB/buf): 16384 + jh*8192 + (wnblk*4 + jloc*2 + ks)*512 + lane*8
// ---------------------------------------------------------------------------
template<int K>
__global__ __launch_bounds__(512, 2)
void gemm_bt(const bf16* __restrict__ A, const bf16* __restrict__ Bt,
             const float* __restrict__ sc, const float* __restrict__ bi,
             bf16* __restrict__ C)
{
    constexpr int NT = K / 64;                 // 4 (K=256) or 8 (K=512)
    __shared__ __align__(16) bf16 L[2][32768]; // 2 x 64KB

    const int tid  = threadIdx.x;
    const int lane = tid & 63;
    const int wid  = tid >> 6;                 // 0..7
    const int wm   = wid >> 2;                 // 0..1
    const int wn   = wid & 3;                  // 0..3
    const int quad = lane >> 4;
    const int l16  = lane & 15;

    // XCD-aware swizzle: 512 blocks, 8 XCDs, 64 consecutive per XCD.
    const int swz = (blockIdx.x & 7) * 64 + (blockIdx.x >> 3);
    const size_t m0 = (size_t)(swz >> 1) * 256;
    const int    n0 = (swz & 1) * 256;

    // staging: this wave covers fragment blocks b0,b1 of each chunk.
    const int b0 = wid * 2, b1 = b0 + 1;
    // A blk b: wmblk=b>>3, iloc=(b>>1)&3, ks=b&1  (ih added per chunk)
    const bf16* pA0 = &A[(m0 + (size_t)((b0 >> 3) * 128 + ((b0 >> 1) & 3) * 16 + l16)) * K + (b0 & 1) * 32 + quad * 8];
    const bf16* pA1 = &A[(m0 + (size_t)((b1 >> 3) * 128 + ((b1 >> 1) & 3) * 16 + l16)) * K + (b1 & 1) * 32 + quad * 8];
    // B blk b: wnblk=b>>2, jloc=(b>>1)&1, ks=b&1  (jh added per chunk)
    const bf16* pB0 = &Bt[(size_t)(n0 + (b0 >> 2) * 64 + ((b0 >> 1) & 1) * 16 + l16) * K + (b0 & 1) * 32 + quad * 8];
    const bf16* pB1 = &Bt[(size_t)(n0 + (b1 >> 2) * 64 + ((b1 >> 1) & 1) * 16 + l16) * K + (b1 & 1) * 32 + quad * 8];

    f32x4  acc[8][4] = {};
    bf16x8 aF[4][2], bF[2][2];

    auto STAGE_A = [&](int kt, int ih, int buf) {
        load_lds16(pA0 + (size_t)ih * 64 * K + kt * 64, &L[buf][ih * 8192 + b0 * 512]);
        load_lds16(pA1 + (size_t)ih * 64 * K + kt * 64, &L[buf][ih * 8192 + b1 * 512]);
    };
    auto STAGE_B = [&](int kt, int jh, int buf) {
        load_lds16(pB0 + (size_t)jh * 32 * K + kt * 64, &L[buf][16384 + jh * 8192 + b0 * 512]);
        load_lds16(pB1 + (size_t)jh * 32 * K + kt * 64, &L[buf][16384 + jh * 8192 + b1 * 512]);
    };
    auto LOAD_A = [&](int cur, int ih) {
        #pragma unroll
        for (int il = 0; il < 4; il++)
            #pragma unroll
            for (int ks = 0; ks < 2; ks++)
                aF[il][ks] = *(const bf16x8*)&L[cur][ih * 8192 + (wm * 8 + il * 2 + ks) * 512 + lane * 8];
    };
    auto LOAD_B = [&](int cur, int jh) {
        #pragma unroll
        for (int jl = 0; jl < 2; jl++)
            #pragma unroll
            for (int ks = 0; ks < 2; ks++)
                bF[jl][ks] = *(const bf16x8*)&L[cur][16384 + jh * 8192 + (wn * 4 + jl * 2 + ks) * 512 + lane * 8];
    };
    auto MFMA16 = [&](int ih, int jh) {
        __builtin_amdgcn_s_setprio(1);
        #pragma unroll
        for (int ks = 0; ks < 2; ks++)
            #pragma unroll
            for (int il = 0; il < 4; il++)
                #pragma unroll
                for (int jl = 0; jl < 2; jl++)
                    acc[ih * 4 + il][jh * 2 + jl] = __builtin_amdgcn_mfma_f32_16x16x32_bf16(
                        aF[il][ks], bF[jl][ks], acc[ih * 4 + il][jh * 2 + jl], 0, 0, 0);
        __builtin_amdgcn_s_setprio(0);
    };

    // prologue: tile 0, chunk order A0,B0,B1,A1 -> buf 0 (8 loads in flight)
    STAGE_A(0, 0, 0); STAGE_B(0, 0, 0); STAGE_B(0, 1, 0); STAGE_A(0, 1, 0);

    for (int t = 0; t < NT - 1; ++t) {
        const int cur = t & 1, nxt = cur ^ 1;
        // phase 0: needs t:A0,t:B0 -> younger: t:B1,t:A1,(t+1:A0) = 6
        STAGE_A(t + 1, 0, nxt);
        asm volatile("s_waitcnt vmcnt(6)" ::: "memory");
        asm volatile("s_barrier" ::: "memory");
        LOAD_A(cur, 0); LOAD_B(cur, 0);
        MFMA16(0, 0);
        __builtin_amdgcn_sched_barrier(0);
        // phase 1: needs t:B1 -> younger: t:A1,(t+1:A0,B0) = 6
        STAGE_B(t + 1, 0, nxt);
        asm volatile("s_waitcnt vmcnt(6)" ::: "memory");
        asm volatile("s_barrier" ::: "memory");
        LOAD_B(cur, 1);
        MFMA16(0, 1);
        __builtin_amdgcn_sched_barrier(0);
        // phase 2: needs t:A1 -> younger: (t+1:A0,B0,B1) = 6
        STAGE_B(t + 1, 1, nxt);
        asm volatile("s_waitcnt vmcnt(6)" ::: "memory");
        asm volatile("s_barrier" ::: "memory");
        LOAD_A(cur, 1); LOAD_B(cur, 0);
        MFMA16(1, 0);
        __builtin_amdgcn_sched_barrier(0);
        // phase 3: needs nothing new
        STAGE_A(t + 1, 1, nxt);
        asm volatile("s_barrier" ::: "memory");
        LOAD_B(cur, 1);
        MFMA16(1, 1);
        __builtin_amdgcn_sched_barrier(0);
    }
    {   // last tile: drain 4 -> 2 -> 0 (no staging)
        const int cur = (NT - 1) & 1;
        asm volatile("s_waitcnt vmcnt(4)" ::: "memory");
        asm volatile("s_barrier" ::: "memory");
        LOAD_A(cur, 0); LOAD_B(cur, 0);
        MFMA16(0, 0);
        __builtin_amdgcn_sched_barrier(0);
        asm volatile("s_waitcnt vmcnt(2)" ::: "memory");
        asm volatile("s_barrier" ::: "memory");
        LOAD_B(cur, 1);
        MFMA16(0, 1);
        __builtin_amdgcn_sched_barrier(0);
        asm volatile("s_waitcnt vmcnt(0)" ::: "memory");
        asm volatile("s_barrier" ::: "memory");
        LOAD_A(cur, 1); LOAD_B(cur, 0);
        MFMA16(1, 0);
        __builtin_amdgcn_sched_barrier(0);
        asm volatile("s_barrier" ::: "memory");
        LOAD_B(cur, 1);
        MFMA16(1, 1);
    }

    // epilogue: C/D layout col = lane&15, row = quad*4 + r  [m89/m91 verified]
    #pragma unroll
    for (int j = 0; j < 4; j++) {
        const int col = n0 + wn * 64 + j * 16 + l16;
        const float s = sc[col], t = bi[col];
        #pragma unroll
        for (int i = 0; i < 8; i++) {
            const size_t rowb = m0 + wm * 128 + i * 16 + quad * 4;
            #pragma unroll
            for (int r = 0; r < 4; r++) {
                float v = acc[i][j][r] * s + t;
                v = v > 0.f ? v : 0.f;
                C[(rowb + r) * 512 + col] = (bf16)v;
            }
        }
    }
}

// ---------------------------------------------------------------------------
// A[N,8] = h4[N,512](bf16) @ Wa[512,8](f32)
// ---------------------------------------------------------------------------
__global__ __launch_bounds__(256)
void compute_A(const bf16* __restrict__ h, const float* __restrict__ Wa,
               float* __restrict__ A)
{
    __shared__ float WaL[512 * 8];
    const int tid = threadIdx.x;
    for (int i = tid; i < 4096; i += 256) WaL[i] = Wa[i];
    __syncthreads();
    const size_t row = (size_t)blockIdx.x * 32 + (tid >> 3);
    const int r = tid & 7;
    const bf16* hp = h + row * 512;
    float acc0 = 0.f, acc1 = 0.f;
    #pragma unroll 4
    for (int k8 = 0; k8 < 64; k8 += 2) {
        bf16x8 h0 = *(const bf16x8*)&hp[k8 * 8];
        bf16x8 h1 = *(const bf16x8*)&hp[k8 * 8 + 8];
        #pragma unroll
        for (int j = 0; j < 8; j++) {
            acc0 += (float)h0[j] * WaL[(k8 * 8 + j) * 8 + r];
            acc1 += (float)h1[j] * WaL[(k8 * 8 + 8 + j) * 8 + r];
        }
    }
    A[row * 8 + r] = acc0 + acc1;
}

// ---------------------------------------------------------------------------
// per-segment softmax over L (8 cols) + penalty. 1024 threads.
// ---------------------------------------------------------------------------
__global__ __launch_bounds__(1024)
void seg_softmax(const float* __restrict__ A, float* __restrict__ Asg,
                 float* __restrict__ pen)
{
    __shared__ float AsL[8192];
    __shared__ float red[1024];
    __shared__ float amax[8], asum[8];
    const int b = blockIdx.x, tid = threadIdx.x;
    const float* Ab = A + (size_t)b * 8192;
    for (int i = tid * 4; i < 8192; i += 4096)
        *(float4*)&AsL[i] = *(const float4*)&Ab[i];
    __syncthreads();
    const int r = tid & 7, chunk = tid >> 3;      // 128 chunks x 8 rows
    float pm = -1e30f;
    for (int l = chunk * 8; l < chunk * 8 + 8; l++) pm = fmaxf(pm, AsL[l * 8 + r]);
    red[tid] = pm;
    __syncthreads();
    if (tid < 512) red[tid] = fmaxf(red[tid], red[tid + 512]); __syncthreads();
    if (tid < 256) red[tid] = fmaxf(red[tid], red[tid + 256]); __syncthreads();
    if (tid < 128) red[tid] = fmaxf(red[tid], red[tid + 128]); __syncthreads();
    if (tid <  64) red[tid] = fmaxf(red[tid], red[tid +  64]); __syncthreads();
    if (tid <  32) red[tid] = fmaxf(red[tid], red[tid +  32]); __syncthreads();
    if (tid <  16) red[tid] = fmaxf(red[tid], red[tid +  16]); __syncthreads();
    if (tid <   8) amax[tid] = fmaxf(red[tid], red[tid + 8]);  __syncthreads();
    const float mr = amax[r];
    float ps = 0.f;
    for (int l = chunk * 8; l < chunk * 8 + 8; l++) {
        float e = expf(AsL[l * 8 + r] - mr);
        AsL[l * 8 + r] = e;
        ps += e;
    }
    red[tid] = ps;
    __syncthreads();
    if (tid < 512) red[tid] += red[tid + 512]; __syncthreads();
    if (tid < 256) red[tid] += red[tid + 256]; __syncthreads();
    if (tid < 128) red[tid] += red[tid + 128]; __syncthreads();
    if (tid <  64) red[tid] += red[tid +  64]; __syncthreads();
    if (tid <  32) red[tid] += red[tid +  32]; __syncthreads();
    if (tid <  16) red[tid] += red[tid +  16]; __syncthreads();
    if (tid <   8) asum[tid] = red[tid] + red[tid + 8];        __syncthreads();
    const float inv = 1.f / asum[r];
    for (int l = chunk * 8; l < chunk * 8 + 8; l++) AsL[l * 8 + r] *= inv;
    __syncthreads();
    for (int i = tid * 4; i < 8192; i += 4096)
        *(float4*)&Asg[(size_t)b * 8192 + i] = *(const float4*)&AsL[i];
    __syncthreads();
    // penalty: 64 (rr,ss) pairs x 16 l-chunks of 64
    {
        const int p = tid & 63, ch = tid >> 6;
        const int rr = p >> 3, ss = p & 7;
        float dot = 0.f;
        for (int l = ch * 64; l < ch * 64 + 64; l++)
            dot += AsL[l * 8 + rr] * AsL[l * 8 + ss];
        red[tid] = dot;
    }
    __syncthreads();
    if (tid < 512) red[tid] += red[tid + 512]; __syncthreads();
    if (tid < 256) red[tid] += red[tid + 256]; __syncthreads();
    if (tid < 128) red[tid] += red[tid + 128]; __syncthreads();
    if (tid < 64) {
        float d = red[tid] + red[tid + 64] - 1.f;
        red[tid] = d * d;
    }
    __syncthreads();
    if (tid == 0) {
        float s = 0.f;
        for (int i = 0; i < 64; i++) s += red[i];
        atomicAdd(pen, s);
    }
}

// ---------------------------------------------------------------------------
// pooled partials: grid (64, 4 col-chunks, 8 l-chunks of 128)
// ---------------------------------------------------------------------------
__global__ __launch_bounds__(256)
void pooled_k(const float* __restrict__ Asg, const bf16* __restrict__ h,
              float* __restrict__ pp)
{
    const int b = blockIdx.x;
    const int cc0 = blockIdx.y * 128;
    const int lc = blockIdx.z;
    const int tid = threadIdx.x;
    const int c = tid & 127, rg = tid >> 7;
    float a0 = 0, a1 = 0, a2 = 0, a3 = 0;
    const float* Asb = Asg + (size_t)b * 8192 + (size_t)lc * 128 * 8 + rg * 4;
    const bf16* hb = h + ((size_t)b * 1024 + lc * 128) * 512 + cc0 + c;
    #pragma unroll 4
    for (int l = 0; l < 128; l++) {
        float4 a = *(const float4*)&Asb[(size_t)l * 8];
        float hv = (float)hb[(size_t)l * 512];
        a0 += a.x * hv; a1 += a.y * hv; a2 += a.z * hv; a3 += a.w * hv;
    }
    float* pb = pp + ((size_t)lc * 64 + b) * 4096 + (rg * 4) * 512 + cc0 + c;
    pb[0] = a0; pb[512] = a1; pb[1024] = a2; pb[1536] = a3;
}

// ---------------------------------------------------------------------------
// head pass 1: z[b][c] += feat-chunk @ Wo1-slice. grid (64, 9)
// kc==8 computes mean/std inline from the convert_stats partials.
// ---------------------------------------------------------------------------
__global__ __launch_bounds__(128)
void head1(const float* __restrict__ pp, const float* __restrict__ p1,
           const float* __restrict__ p2, const float* __restrict__ Wo1,
           float* __restrict__ zbuf)
{
    __shared__ float f[512];
    const int b = blockIdx.x, kc = blockIdx.y, tid = threadIdx.x;
    if (kc < 8) {
        for (int j = tid; j < 512; j += 128) {
            const size_t i = (size_t)kc * 512 + j;
            float s = 0.f;
            #pragma unroll
            for (int lc = 0; lc < 8; lc++)
                s += pp[((size_t)lc * 64 + b) * 4096 + i];
            f[j] = s;
        }
    } else {
        for (int j = tid; j < 256; j += 128) {
            float s = 0.f, s2 = 0.f;
            #pragma unroll
            for (int lc = 0; lc < 16; lc++) {
                s  += p1[((size_t)lc * 64 + b) * 256 + j];
                s2 += p2[((size_t)lc * 64 + b) * 256 + j];
            }
            float m = s * (1.f / 1024.f);
            float var = (s2 - s * m) * (1.f / 1023.f);
            f[j]       = m;
            f[256 + j] = sqrtf(fmaxf(var, 0.f));
        }
    }
    __syncthreads();
    const float* Wp = Wo1 + (size_t)kc * 512 * 128 + tid;
    float z = 0.f;
    #pragma unroll 8
    for (int j = 0; j < 512; j++) z += f[j] * Wp[(size_t)j * 128];
    atomicAdd(&zbuf[b * 128 + tid], z);
}

// ---------------------------------------------------------------------------
// head pass 2: BN+relu -> @ Wo2 -> log_softmax; b==0 writes penalty
// ---------------------------------------------------------------------------
__global__ __launch_bounds__(128)
void head2(const float* __restrict__ zbuf, const float* __restrict__ bo1,
           const float* __restrict__ go, const float* __restrict__ beo,
           const float* __restrict__ mo, const float* __restrict__ vo,
           const float* __restrict__ Wo2, const float* __restrict__ bo2,
           const float* __restrict__ pen, float* __restrict__ out)
{
    __shared__ float o[128];
    __shared__ float lg[4];
    const int b = blockIdx.x, tid = threadIdx.x;
    float z = zbuf[b * 128 + tid];
    float s = go[tid] * rsqrtf(vo[tid] + EPS);
    float t = (bo1[tid] - mo[tid]) * s + beo[tid];
    float ov = z * s + t;
    o[tid] = ov > 0.f ? ov : 0.f;
    __syncthreads();
    if (tid < 4) {
        float acc = bo2[tid];
        for (int j = 0; j < 128; j++) acc += o[j] * Wo2[j * 4 + tid];
        lg[tid] = acc;
    }
    __syncthreads();
    if (tid == 0) {
        float m = fmaxf(fmaxf(lg[0], lg[1]), fmaxf(lg[2], lg[3]));
        float sum = 0.f;
        for (int k = 0; k < 4; k++) sum += expf(lg[k] - m);
        float lse = m + logf(sum);
        for (int k = 0; k < 4; k++) out[b * 4 + k] = lg[k] - lse;
        if (b == 0) out[256] = pen[0];
    }
}

// ---------------------------------------------------------------------------
extern "C" void kernel_launch(void* const* d_in, const int* in_sizes, int n_in,
                              void* d_out, int out_size, void* d_ws, size_t ws_size,
                              hipStream_t stream)
{
    const float* x   = (const float*)d_in[0];
    const float* Wa  = (const float*)d_in[2];
    const float* Wo1 = (const float*)d_in[3];
    const float* bo1 = (const float*)d_in[4];
    const float* go  = (const float*)d_in[5];
    const float* beo = (const float*)d_in[6];
    const float* mo  = (const float*)d_in[7];
    const float* vo  = (const float*)d_in[8];
    const float* Wo2 = (const float*)d_in[9];
    const float* bo2 = (const float*)d_in[10];
    const float *W[4], *bb[4], *gg[4], *be[4], *mm[4], *vv[4];
    for (int l = 0; l < 4; l++) {
        W[l]  = (const float*)d_in[11 + 6 * l + 0];
        bb[l] = (const float*)d_in[11 + 6 * l + 1];
        gg[l] = (const float*)d_in[11 + 6 * l + 2];
        be[l] = (const float*)d_in[11 + 6 * l + 3];
        mm[l] = (const float*)d_in[11 + 6 * l + 4];
        vv[l] = (const float*)d_in[11 + 6 * l + 5];
    }

    char* w = (char*)d_ws;
    bf16* xb  = (bf16*)w;  w += (size_t)65536 * 256 * 2;   // 32 MB
    bf16* hA  = (bf16*)w;  w += (size_t)65536 * 512 * 2;   // 64 MB
    bf16* hB  = (bf16*)w;  w += (size_t)65536 * 512 * 2;   // 64 MB
    bf16* w1t = (bf16*)w;  w += (size_t)512 * 256 * 2;
    bf16* w2t = (bf16*)w;  w += (size_t)512 * 512 * 2;
    bf16* w3t = (bf16*)w;  w += (size_t)512 * 512 * 2;
    bf16* w4t = (bf16*)w;  w += (size_t)512 * 512 * 2;
    float* sb = (float*)w; w += (size_t)4 * 1024 * 4;      // [layer][s|t][512]
    float* Ab = (float*)w; w += (size_t)65536 * 8 * 4;
    float* As = (float*)w; w += (size_t)65536 * 8 * 4;
    float* pp = (float*)w; w += (size_t)8 * 64 * 4096 * 4; // pooled partials
    float* p1 = (float*)w; w += (size_t)16 * 64 * 256 * 4;
    float* p2 = (float*)w; w += (size_t)16 * 64 * 256 * 4;
    float* zbuf = (float*)w; w += (size_t)64 * 128 * 4;
    float* pen = (float*)w;

    hipMemsetAsync(zbuf, 0, (64 * 128 + 1) * sizeof(float), stream); // zbuf + pen

    convert_stats<<<dim3(64, 16), 256, 0, stream>>>(x, xb, p1, p2);
    prep_all<<<3592, 256, 0, stream>>>(
        W[0], W[1], W[2], W[3], w1t, w2t, w3t, w4t,
        bb[0], gg[0], be[0], mm[0], vv[0],
        bb[1], gg[1], be[1], mm[1], vv[1],
        bb[2], gg[2], be[2], mm[2], vv[2],
        bb[3], gg[3], be[3], mm[3], vv[3], sb);

    gemm_bt<256><<<512, 512, 0, stream>>>(xb, w1t, sb + 0,    sb + 512,  hA);
    gemm_bt<512><<<512, 512, 0, stream>>>(hA, w2t, sb + 1024, sb + 1536, hB);
    gemm_bt<512><<<512, 512, 0, stream>>>(hB, w3t, sb + 2048, sb + 2560, hA);
    gemm_bt<512><<<512, 512, 0, stream>>>(hA, w4t, sb + 3072, sb + 3584, hB);

    compute_A<<<2048, 256, 0, stream>>>(hB, Wa, Ab);
    seg_softmax<<<64, 1024, 0, stream>>>(Ab, As, pen);
    pooled_k<<<dim3(64, 4, 8), 256, 0, stream>>>(As, hB, pp);
    head1<<<dim3(64, 9), 128, 0, stream>>>(pp, p1, p2, Wo1, zbuf);
    head2<<<64, 128, 0, stream>>>(zbuf, bo1, go, beo, mo, vo, Wo2, bo2,
                                  pen, (float*)d_out);
}

// Round 5
// 471.111 us; speedup vs baseline: 1.6222x; 1.0994x over previous
//
#include <hip/hip_runtime.h>
#include <cstdint>
#include <cstddef>

typedef __bf16 bf16;
typedef __bf16 bf16x4 __attribute__((ext_vector_type(4)));
typedef __bf16 bf16x8 __attribute__((ext_vector_type(8)));
typedef float  f32x4  __attribute__((ext_vector_type(4)));
typedef unsigned int uint;

#define EPS 1e-5f

// ---------------------------------------------------------------------------
// async global->LDS, 16B per lane. LDS dest is wave-uniform base + lane*16.
// ---------------------------------------------------------------------------
__device__ __forceinline__ void load_lds16(const void* g, void* l) {
    typedef __attribute__((address_space(1))) void gvoid;
    typedef __attribute__((address_space(3))) void lvoid;
    gvoid* gp = (gvoid*)(unsigned long long)(uintptr_t)g;
    lvoid* lp = (lvoid*)(unsigned int)(uintptr_t)l;
    __builtin_amdgcn_global_load_lds(gp, lp, 16, 0, 0);
}

// ---------------------------------------------------------------------------
// fused: x -> bf16 copy + per-(b,d) partial sums for mean/std. grid (64,16)
// ---------------------------------------------------------------------------
__global__ __launch_bounds__(256)
void convert_stats(const float* __restrict__ x, bf16* __restrict__ xb,
                   float* __restrict__ p1, float* __restrict__ p2)
{
    const int b = blockIdx.x, lc = blockIdx.y, d = threadIdx.x;
    const size_t base = ((size_t)b * 1024 + lc * 64) * 256;
    float s = 0.f, s2 = 0.f;
    #pragma unroll 4
    for (int l = 0; l < 64; l++) {
        float v = x[base + (size_t)l * 256 + d];
        xb[base + (size_t)l * 256 + d] = (bf16)v;
        s += v; s2 += v * v;
    }
    p1[((size_t)lc * 64 + b) * 256 + d] = s;
    p2[((size_t)lc * 64 + b) * 256 + d] = s2;
}

// ---------------------------------------------------------------------------
// all weight prep in ONE dispatch: 4 transposes + 4 scale/bias. 3592 blocks.
// ---------------------------------------------------------------------------
__global__ void prep_all(
    const float* __restrict__ W1, const float* __restrict__ W2,
    const float* __restrict__ W3, const float* __restrict__ W4,
    bf16* __restrict__ t1, bf16* __restrict__ t2,
    bf16* __restrict__ t3, bf16* __restrict__ t4,
    const float* b1, const float* g1, const float* be1, const float* m1, const float* v1,
    const float* b2, const float* g2, const float* be2, const float* m2, const float* v2,
    const float* b3, const float* g3, const float* be3, const float* m3, const float* v3,
    const float* b4, const float* g4, const float* be4, const float* m4, const float* v4,
    float* __restrict__ sb)
{
    const int bid = blockIdx.x, tid = threadIdx.x;
    if (bid < 512) {                       // W1: 512x256 (Wt[n][k])
        int idx = bid * 256 + tid;
        int n = idx >> 8, k = idx & 255;
        t1[idx] = (bf16)W1[k * 512 + n];
    } else if (bid < 3584) {               // W2/W3/W4: 512x512 each
        int r = bid - 512;
        int which = r >> 10;               // 1024 blocks each
        int idx = (r & 1023) * 256 + tid;
        int n = idx >> 9, k = idx & 511;
        const float* W = which == 0 ? W2 : (which == 1 ? W3 : W4);
        bf16* Wt       = which == 0 ? t2 : (which == 1 ? t3 : t4);
        Wt[idx] = (bf16)W[k * 512 + n];
    } else {                               // scale/bias: 8 blocks
        int r = bid - 3584;
        int lay = r >> 1;
        int j = (r & 1) * 256 + tid;
        const float *b, *g, *be, *m, *v;
        switch (lay) {
            case 0: b=b1; g=g1; be=be1; m=m1; v=v1; break;
            case 1: b=b2; g=g2; be=be2; m=m2; v=v2; break;
            case 2: b=b3; g=g3; be=be3; m=m3; v=v3; break;
            default:b=b4; g=g4; be=be4; m=m4; v=v4; break;
        }
        float sj = g[j] * rsqrtf(v[j] + EPS);
        sb[lay * 1024 + j]       = sj;
        sb[lay * 1024 + 512 + j] = (b[j] - m[j]) * sj + be[j];
    }
}

// ---------------------------------------------------------------------------
// GEMM: C[M,512] = relu( (A[M,K] @ Wt[512,K]^T) * s + t ), bf16 out
//
// m201-faithful phased schedule (T2+T3+T4+T5): 256x256 tile, BK=64, 512 thr
// = 8 waves (2m x 4n), wave tile 128x64, acc[8][4] f32x4, LDS 2x64KB dbuf.
//
// KEY vs round-4 (which was flat at 64us): phase-top ds_reads target a chunk
// validated by the PREVIOUS phase's vmcnt+barrier, so this phase's
// vmcnt-wait + barrier-rendezvous hides the LDS read latency; NO
// sched_barrier(0) (m141: order-pinning defeats the scheduler); 3 barriers
// per tile, lgkmcnt(0) only after a barrier; counted vmcnt(4) never drains
// to 0 mid-loop (2 loads/chunk, issue order A0,B0,B1,A1 == consumption).
//
// vmcnt ledger (steady state, per wave, 2 loads per chunk):
//   ph0: +stage(t+1:A0) -> out {t:B1,A1, +1:A0}=6 -> vmcnt(4) validates t:B1
//   ph1: +stage(t+1:B0) -> out {t:A1, +1:A0,B0}=6 -> vmcnt(4) validates t:A1
//   ph2: +stage(t+1:B1) -> out 6, nothing to validate, NO barrier
//   ph3: +stage(t+1:A1) -> out 8 -> vmcnt(4) validates t+1:A0,B0 (next ph0)
// Cross-tile WAR safe: a wave stages into buf[b] only after the ph3 barrier
// of the tile whose reads of buf[b] were all lgkmcnt-drained before it.
//
// Epilogue: K-loop leaves LDS dead; 128KB == the 256x256 bf16 C tile.
// acc -> LDS (b16 writes, 2-way aliasing = free), barrier, linear readback,
// coalesced bf16x8 global stores (fixes the 2x write amplification of the
// old 32B-scattered short stores: WRITE_SIZE 120MB -> ~67MB).
// ---------------------------------------------------------------------------
template<int K>
__global__ __launch_bounds__(512, 2)
void gemm_bt(const bf16* __restrict__ A, const bf16* __restrict__ Bt,
             const float* __restrict__ sc, const float* __restrict__ bi,
             bf16* __restrict__ C)
{
    constexpr int NT = K / 64;                 // 4 (K=256) or 8 (K=512)
    __shared__ __align__(16) bf16 L[2][32768]; // 2 x 64KB

    const int tid  = threadIdx.x;
    const int lane = tid & 63;
    const int wid  = tid >> 6;                 // 0..7
    const int wm   = wid >> 2;                 // 0..1
    const int wn   = wid & 3;                  // 0..3
    const int quad = lane >> 4;
    const int l16  = lane & 15;

    // XCD-aware swizzle: 512 blocks, 8 XCDs, 64 consecutive per XCD.
    const int swz = (blockIdx.x & 7) * 64 + (blockIdx.x >> 3);
    const size_t m0 = (size_t)(swz >> 1) * 256;
    const int    n0 = (swz & 1) * 256;

    // staging: this wave covers fragment blocks b0,b1 of each chunk.
    const int b0 = wid * 2, b1 = b0 + 1;
    const bf16* pA0 = &A[(m0 + (size_t)((b0 >> 3) * 128 + ((b0 >> 1) & 3) * 16 + l16)) * K + (b0 & 1) * 32 + quad * 8];
    const bf16* pA1 = &A[(m0 + (size_t)((b1 >> 3) * 128 + ((b1 >> 1) & 3) * 16 + l16)) * K + (b1 & 1) * 32 + quad * 8];
    const bf16* pB0 = &Bt[(size_t)(n0 + (b0 >> 2) * 64 + ((b0 >> 1) & 1) * 16 + l16) * K + (b0 & 1) * 32 + quad * 8];
    const bf16* pB1 = &Bt[(size_t)(n0 + (b1 >> 2) * 64 + ((b1 >> 1) & 1) * 16 + l16) * K + (b1 & 1) * 32 + quad * 8];

    f32x4  acc[8][4] = {};
    bf16x8 aF[4][2], bF0[2][2], bF1[2][2];

    auto STAGE_A = [&](int kt, int ih, int buf) {
        load_lds16(pA0 + (size_t)ih * 64 * K + kt * 64, &L[buf][ih * 8192 + b0 * 512]);
        load_lds16(pA1 + (size_t)ih * 64 * K + kt * 64, &L[buf][ih * 8192 + b1 * 512]);
    };
    auto STAGE_B = [&](int kt, int jh, int buf) {
        load_lds16(pB0 + (size_t)jh * 32 * K + kt * 64, &L[buf][16384 + jh * 8192 + b0 * 512]);
        load_lds16(pB1 + (size_t)jh * 32 * K + kt * 64, &L[buf][16384 + jh * 8192 + b1 * 512]);
    };
    auto LOAD_A = [&](int cur, int ih) {
        #pragma unroll
        for (int il = 0; il < 4; il++)
            #pragma unroll
            for (int ks = 0; ks < 2; ks++)
                aF[il][ks] = *(const bf16x8*)&L[cur][ih * 8192 + (wm * 8 + il * 2 + ks) * 512 + lane * 8];
    };
    auto LOAD_B = [&](int cur, int jh, bf16x8 (&bf)[2][2]) {
        #pragma unroll
        for (int jl = 0; jl < 2; jl++)
            #pragma unroll
            for (int ks = 0; ks < 2; ks++)
                bf[jl][ks] = *(const bf16x8*)&L[cur][16384 + jh * 8192 + (wn * 4 + jl * 2 + ks) * 512 + lane * 8];
    };
    auto MFMA16 = [&](int ih, int jh, bf16x8 (&bf)[2][2]) {
        __builtin_amdgcn_s_setprio(1);
        #pragma unroll
        for (int ks = 0; ks < 2; ks++)
            #pragma unroll
            for (int il = 0; il < 4; il++)
                #pragma unroll
                for (int jl = 0; jl < 2; jl++)
                    acc[ih * 4 + il][jh * 2 + jl] = __builtin_amdgcn_mfma_f32_16x16x32_bf16(
                        aF[il][ks], bf[jl][ks], acc[ih * 4 + il][jh * 2 + jl], 0, 0, 0);
        __builtin_amdgcn_s_setprio(0);
    };

    // prologue: stage tile 0 (chunks A0,B0,B1,A1), validate A0,B0.
    STAGE_A(0, 0, 0); STAGE_B(0, 0, 0); STAGE_B(0, 1, 0); STAGE_A(0, 1, 0);
    asm volatile("s_waitcnt vmcnt(4)" ::: "memory");
    asm volatile("s_barrier" ::: "memory");

    for (int t = 0; t < NT; ++t) {
        const int cur = t & 1, nxt = cur ^ 1;
        const bool last = (t == NT - 1);
        // ---- phase 0: reads A0,B0 (validated prev ph3) ; MFMA(0,0)
        LOAD_A(cur, 0);
        LOAD_B(cur, 0, bF0);
        if (!last) {
            STAGE_A(t + 1, 0, nxt);
            asm volatile("s_waitcnt vmcnt(4)" ::: "memory");   // validates t:B1
        } else {
            asm volatile("s_waitcnt vmcnt(2)" ::: "memory");   // validates t:B1
        }
        asm volatile("s_barrier" ::: "memory");
        asm volatile("s_waitcnt lgkmcnt(0)" ::: "memory");
        MFMA16(0, 0, bF0);
        // ---- phase 1: reads B1 (validated ph0) ; MFMA(0,1)
        LOAD_B(cur, 1, bF1);
        if (!last) {
            STAGE_B(t + 1, 0, nxt);
            asm volatile("s_waitcnt vmcnt(4)" ::: "memory");   // validates t:A1
        } else {
            asm volatile("s_waitcnt vmcnt(0)" ::: "memory");   // validates t:A1
        }
        asm volatile("s_barrier" ::: "memory");
        asm volatile("s_waitcnt lgkmcnt(0)" ::: "memory");
        MFMA16(0, 1, bF1);
        // ---- phase 2: reads A1 (validated ph1) ; no barrier needed
        LOAD_A(cur, 1);
        if (!last) STAGE_B(t + 1, 1, nxt);
        asm volatile("s_waitcnt lgkmcnt(0)" ::: "memory");
        MFMA16(1, 0, bF0);
        // ---- phase 3: no reads ; validate t+1:A0,B0 for next ph0
        if (!last) {
            STAGE_A(t + 1, 1, nxt);
            asm volatile("s_waitcnt vmcnt(4)" ::: "memory");   // validates t+1:A0,B0
            asm volatile("s_barrier" ::: "memory");
        }
        MFMA16(1, 1, bF1);
    }

    // ---- epilogue: acc -> LDS (BN+relu fused) -> coalesced bf16x8 stores
    __syncthreads();                       // all waves done with K-loop LDS
    bf16* Lf = &L[0][0];                   // 65536 bf16 = full 256x256 C tile
    #pragma unroll
    for (int j = 0; j < 4; j++) {
        const int col = wn * 64 + j * 16 + l16;
        const float s = sc[n0 + col], t = bi[n0 + col];
        #pragma unroll
        for (int i = 0; i < 8; i++) {
            const int rowb = wm * 128 + i * 16 + quad * 4;
            #pragma unroll
            for (int r = 0; r < 4; r++) {
                float v = acc[i][j][r] * s + t;
                Lf[(rowb + r) * 256 + col] = (bf16)(v > 0.f ? v : 0.f);
            }
        }
    }
    __syncthreads();
    #pragma unroll
    for (int c = 0; c < 16; c++) {
        const int e = c * 4096 + tid * 8;
        const int row = e >> 8, col = e & 255;
        *(bf16x8*)&C[(m0 + row) * 512 + n0 + col] = *(const bf16x8*)&Lf[e];
    }
}

// ---------------------------------------------------------------------------
// A[N,8] = h4[N,512](bf16) @ Wa[512,8](f32)
// ---------------------------------------------------------------------------
__global__ __launch_bounds__(256)
void compute_A(const bf16* __restrict__ h, const float* __restrict__ Wa,
               float* __restrict__ A)
{
    __shared__ float WaL[512 * 8];
    const int tid = threadIdx.x;
    for (int i = tid; i < 4096; i += 256) WaL[i] = Wa[i];
    __syncthreads();
    const size_t row = (size_t)blockIdx.x * 32 + (tid >> 3);
    const int r = tid & 7;
    const bf16* hp = h + row * 512;
    float acc0 = 0.f, acc1 = 0.f;
    #pragma unroll 4
    for (int k8 = 0; k8 < 64; k8 += 2) {
        bf16x8 h0 = *(const bf16x8*)&hp[k8 * 8];
        bf16x8 h1 = *(const bf16x8*)&hp[k8 * 8 + 8];
        #pragma unroll
        for (int j = 0; j < 8; j++) {
            acc0 += (float)h0[j] * WaL[(k8 * 8 + j) * 8 + r];
            acc1 += (float)h1[j] * WaL[(k8 * 8 + 8 + j) * 8 + r];
        }
    }
    A[row * 8 + r] = acc0 + acc1;
}

// ---------------------------------------------------------------------------
// per-segment softmax over L (8 cols) + penalty. 1024 threads.
// ---------------------------------------------------------------------------
__global__ __launch_bounds__(1024)
void seg_softmax(const float* __restrict__ A, float* __restrict__ Asg,
                 float* __restrict__ pen)
{
    __shared__ float AsL[8192];
    __shared__ float red[1024];
    __shared__ float amax[8], asum[8];
    const int b = blockIdx.x, tid = threadIdx.x;
    const float* Ab = A + (size_t)b * 8192;
    for (int i = tid * 4; i < 8192; i += 4096)
        *(float4*)&AsL[i] = *(const float4*)&Ab[i];
    __syncthreads();
    const int r = tid & 7, chunk = tid >> 3;      // 128 chunks x 8 rows
    float pm = -1e30f;
    for (int l = chunk * 8; l < chunk * 8 + 8; l++) pm = fmaxf(pm, AsL[l * 8 + r]);
    red[tid] = pm;
    __syncthreads();
    if (tid < 512) red[tid] = fmaxf(red[tid], red[tid + 512]); __syncthreads();
    if (tid < 256) red[tid] = fmaxf(red[tid], red[tid + 256]); __syncthreads();
    if (tid < 128) red[tid] = fmaxf(red[tid], red[tid + 128]); __syncthreads();
    if (tid <  64) red[tid] = fmaxf(red[tid], red[tid +  64]); __syncthreads();
    if (tid <  32) red[tid] = fmaxf(red[tid], red[tid +  32]); __syncthreads();
    if (tid <  16) red[tid] = fmaxf(red[tid], red[tid +  16]); __syncthreads();
    if (tid <   8) amax[tid] = fmaxf(red[tid], red[tid + 8]);  __syncthreads();
    const float mr = amax[r];
    float ps = 0.f;
    for (int l = chunk * 8; l < chunk * 8 + 8; l++) {
        float e = expf(AsL[l * 8 + r] - mr);
        AsL[l * 8 + r] = e;
        ps += e;
    }
    red[tid] = ps;
    __syncthreads();
    if (tid < 512) red[tid] += red[tid + 512]; __syncthreads();
    if (tid < 256) red[tid] += red[tid + 256]; __syncthreads();
    if (tid < 128) red[tid] += red[tid + 128]; __syncthreads();
    if (tid <  64) red[tid] += red[tid +  64]; __syncthreads();
    if (tid <  32) red[tid] += red[tid +  32]; __syncthreads();
    if (tid <  16) red[tid] += red[tid +  16]; __syncthreads();
    if (tid <   8) asum[tid] = red[tid] + red[tid + 8];        __syncthreads();
    const float inv = 1.f / asum[r];
    for (int l = chunk * 8; l < chunk * 8 + 8; l++) AsL[l * 8 + r] *= inv;
    __syncthreads();
    for (int i = tid * 4; i < 8192; i += 4096)
        *(float4*)&Asg[(size_t)b * 8192 + i] = *(const float4*)&AsL[i];
    __syncthreads();
    // penalty: 64 (rr,ss) pairs x 16 l-chunks of 64
    {
        const int p = tid & 63, ch = tid >> 6;
        const int rr = p >> 3, ss = p & 7;
        float dot = 0.f;
        for (int l = ch * 64; l < ch * 64 + 64; l++)
            dot += AsL[l * 8 + rr] * AsL[l * 8 + ss];
        red[tid] = dot;
    }
    __syncthreads();
    if (tid < 512) red[tid] += red[tid + 512]; __syncthreads();
    if (tid < 256) red[tid] += red[tid + 256]; __syncthreads();
    if (tid < 128) red[tid] += red[tid + 128]; __syncthreads();
    if (tid < 64) {
        float d = red[tid] + red[tid + 64] - 1.f;
        red[tid] = d * d;
    }
    __syncthreads();
    if (tid == 0) {
        float s = 0.f;
        for (int i = 0; i < 64; i++) s += red[i];
        atomicAdd(pen, s);
    }
}

// ---------------------------------------------------------------------------
// pooled partials: grid (64, 4 col-chunks, 8 l-chunks of 128)
// ---------------------------------------------------------------------------
__global__ __launch_bounds__(256)
void pooled_k(const float* __restrict__ Asg, const bf16* __restrict__ h,
              float* __restrict__ pp)
{
    const int b = blockIdx.x;
    const int cc0 = blockIdx.y * 128;
    const int lc = blockIdx.z;
    const int tid = threadIdx.x;
    const int c = tid & 127, rg = tid >> 7;
    float a0 = 0, a1 = 0, a2 = 0, a3 = 0;
    const float* Asb = Asg + (size_t)b * 8192 + (size_t)lc * 128 * 8 + rg * 4;
    const bf16* hb = h + ((size_t)b * 1024 + lc * 128) * 512 + cc0 + c;
    #pragma unroll 4
    for (int l = 0; l < 128; l++) {
        float4 a = *(const float4*)&Asb[(size_t)l * 8];
        float hv = (float)hb[(size_t)l * 512];
        a0 += a.x * hv; a1 += a.y * hv; a2 += a.z * hv; a3 += a.w * hv;
    }
    float* pb = pp + ((size_t)lc * 64 + b) * 4096 + (rg * 4) * 512 + cc0 + c;
    pb[0] = a0; pb[512] = a1; pb[1024] = a2; pb[1536] = a3;
}

// ---------------------------------------------------------------------------
// head pass 1: z[b][c] += feat-chunk @ Wo1-slice. grid (64, 9)
// kc==8 computes mean/std inline from the convert_stats partials.
// ---------------------------------------------------------------------------
__global__ __launch_bounds__(128)
void head1(const float* __restrict__ pp, const float* __restrict__ p1,
           const float* __restrict__ p2, const float* __restrict__ Wo1,
           float* __restrict__ zbuf)
{
    __shared__ float f[512];
    const int b = blockIdx.x, kc = blockIdx.y, tid = threadIdx.x;
    if (kc < 8) {
        for (int j = tid; j < 512; j += 128) {
            const size_t i = (size_t)kc * 512 + j;
            float s = 0.f;
            #pragma unroll
            for (int lc = 0; lc < 8; lc++)
                s += pp[((size_t)lc * 64 + b) * 4096 + i];
            f[j] = s;
        }
    } else {
        for (int j = tid; j < 256; j += 128) {
            float s = 0.f, s2 = 0.f;
            #pragma unroll
            for (int lc = 0; lc < 16; lc++) {
                s  += p1[((size_t)lc * 64 + b) * 256 + j];
                s2 += p2[((size_t)lc * 64 + b) * 256 + j];
            }
            float m = s * (1.f / 1024.f);
            float var = (s2 - s * m) * (1.f / 1023.f);
            f[j]       = m;
            f[256 + j] = sqrtf(fmaxf(var, 0.f));
        }
    }
    __syncthreads();
    const float* Wp = Wo1 + (size_t)kc * 512 * 128 + tid;
    float z = 0.f;
    #pragma unroll 8
    for (int j = 0; j < 512; j++) z += f[j] * Wp[(size_t)j * 128];
    atomicAdd(&zbuf[b * 128 + tid], z);
}

// ---------------------------------------------------------------------------
// head pass 2: BN+relu -> @ Wo2 -> log_softmax; b==0 writes penalty
// ---------------------------------------------------------------------------
__global__ __launch_bounds__(128)
void head2(const float* __restrict__ zbuf, const float* __restrict__ bo1,
           const float* __restrict__ go, const float* __restrict__ beo,
           const float* __restrict__ mo, const float* __restrict__ vo,
           const float* __restrict__ Wo2, const float* __restrict__ bo2,
           const float* __restrict__ pen, float* __restrict__ out)
{
    __shared__ float o[128];
    __shared__ float lg[4];
    const int b = blockIdx.x, tid = threadIdx.x;
    float z = zbuf[b * 128 + tid];
    float s = go[tid] * rsqrtf(vo[tid] + EPS);
    float t = (bo1[tid] - mo[tid]) * s + beo[tid];
    float ov = z * s + t;
    o[tid] = ov > 0.f ? ov : 0.f;
    __syncthreads();
    if (tid < 4) {
        float acc = bo2[tid];
        for (int j = 0; j < 128; j++) acc += o[j] * Wo2[j * 4 + tid];
        lg[tid] = acc;
    }
    __syncthreads();
    if (tid == 0) {
        float m = fmaxf(fmaxf(lg[0], lg[1]), fmaxf(lg[2], lg[3]));
        float sum = 0.f;
        for (int k = 0; k < 4; k++) sum += expf(lg[k] - m);
        float lse = m + logf(sum);
        for (int k = 0; k < 4; k++) out[b * 4 + k] = lg[k] - lse;
        if (b == 0) out[256] = pen[0];
    }
}

// ---------------------------------------------------------------------------
extern "C" void kernel_launch(void* const* d_in, const int* in_sizes, int n_in,
                              void* d_out, int out_size, void* d_ws, size_t ws_size,
                              hipStream_t stream)
{
    const float* x   = (const float*)d_in[0];
    const float* Wa  = (const float*)d_in[2];
    const float* Wo1 = (const float*)d_in[3];
    const float* bo1 = (const float*)d_in[4];
    const float* go  = (const float*)d_in[5];
    const float* beo = (const float*)d_in[6];
    const float* mo  = (const float*)d_in[7];
    const float* vo  = (const float*)d_in[8];
    const float* Wo2 = (const float*)d_in[9];
    const float* bo2 = (const float*)d_in[10];
    const float *W[4], *bb[4], *gg[4], *be[4], *mm[4], *vv[4];
    for (int l = 0; l < 4; l++) {
        W[l]  = (const float*)d_in[11 + 6 * l + 0];
        bb[l] = (const float*)d_in[11 + 6 * l + 1];
        gg[l] = (const float*)d_in[11 + 6 * l + 2];
        be[l] = (const float*)d_in[11 + 6 * l + 3];
        mm[l] = (const float*)d_in[11 + 6 * l + 4];
        vv[l] = (const float*)d_in[11 + 6 * l + 5];
    }

    char* w = (char*)d_ws;
    bf16* xb  = (bf16*)w;  w += (size_t)65536 * 256 * 2;   // 32 MB
    bf16* hA  = (bf16*)w;  w += (size_t)65536 * 512 * 2;   // 64 MB
    bf16* hB  = (bf16*)w;  w += (size_t)65536 * 512 * 2;   // 64 MB
    bf16* w1t = (bf16*)w;  w += (size_t)512 * 256 * 2;
    bf16* w2t = (bf16*)w;  w += (size_t)512 * 512 * 2;
    bf16* w3t = (bf16*)w;  w += (size_t)512 * 512 * 2;
    bf16* w4t = (bf16*)w;  w += (size_t)512 * 512 * 2;
    float* sb = (float*)w; w += (size_t)4 * 1024 * 4;      // [layer][s|t][512]
    float* Ab = (float*)w; w += (size_t)65536 * 8 * 4;
    float* As = (float*)w; w += (size_t)65536 * 8 * 4;
    float* pp = (float*)w; w += (size_t)8 * 64 * 4096 * 4; // pooled partials
    float* p1 = (float*)w; w += (size_t)16 * 64 * 256 * 4;
    float* p2 = (float*)w; w += (size_t)16 * 64 * 256 * 4;
    float* zbuf = (float*)w; w += (size_t)64 * 128 * 4;
    float* pen = (float*)w;

    hipMemsetAsync(zbuf, 0, (64 * 128 + 1) * sizeof(float), stream); // zbuf + pen

    convert_stats<<<dim3(64, 16), 256, 0, stream>>>(x, xb, p1, p2);
    prep_all<<<3592, 256, 0, stream>>>(
        W[0], W[1], W[2], W[3], w1t, w2t, w3t, w4t,
        bb[0], gg[0], be[0], mm[0], vv[0],
        bb[1], gg[1], be[1], mm[1], vv[1],
        bb[2], gg[2], be[2], mm[2], vv[2],
        bb[3], gg[3], be[3], mm[3], vv[3], sb);

    gemm_bt<256><<<512, 512, 0, stream>>>(xb, w1t, sb + 0,    sb + 512,  hA);
    gemm_bt<512><<<512, 512, 0, stream>>>(hA, w2t, sb + 1024, sb + 1536, hB);
    gemm_bt<512><<<512, 512, 0, stream>>>(hB, w3t, sb + 2048, sb + 2560, hA);
    gemm_bt<512><<<512, 512, 0, stream>>>(hA, w4t, sb + 3072, sb + 3584, hB);

    compute_A<<<2048, 256, 0, stream>>>(hB, Wa, Ab);
    seg_softmax<<<64, 1024, 0, stream>>>(Ab, As, pen);
    pooled_k<<<dim3(64, 4, 8), 256, 0, stream>>>(As, hB, pp);
    head1<<<dim3(64, 9), 128, 0, stream>>>(pp, p1, p2, Wo1, zbuf);
    head2<<<64, 128, 0, stream>>>(zbuf, bo1, go, beo, mo, vo, Wo2, bo2,
                                  pen, (float*)d_out);
}

// Round 6
// 437.671 us; speedup vs baseline: 1.7461x; 1.0764x over previous
//
#include <hip/hip_runtime.h>
#include <cstdint>
#include <cstddef>

typedef __bf16 bf16;
typedef __bf16 bf16x4 __attribute__((ext_vector_type(4)));
typedef __bf16 bf16x8 __attribute__((ext_vector_type(8)));
typedef float  f32x4  __attribute__((ext_vector_type(4)));
typedef unsigned int uint;

#define EPS 1e-5f

// ---------------------------------------------------------------------------
// async global->LDS, 16B per lane. LDS dest is wave-uniform base + lane*16.
// ---------------------------------------------------------------------------
__device__ __forceinline__ void load_lds16(const void* g, void* l) {
    typedef __attribute__((address_space(1))) void gvoid;
    typedef __attribute__((address_space(3))) void lvoid;
    gvoid* gp = (gvoid*)(unsigned long long)(uintptr_t)g;
    lvoid* lp = (lvoid*)(unsigned int)(uintptr_t)l;
    __builtin_amdgcn_global_load_lds(gp, lp, 16, 0, 0);
}

// ---------------------------------------------------------------------------
// fused: x -> bf16 copy + per-(b,d) partial sums for mean/std. grid (64,16).
// v2: float4 loads (16B/lane, was 4B scalar), bf16x4 stores, 4-rowgroup
// LDS reduce. p1/p2 layout unchanged -> head1 untouched.
// ---------------------------------------------------------------------------
__global__ __launch_bounds__(256)
void convert_stats(const float* __restrict__ x, bf16* __restrict__ xb,
                   float* __restrict__ p1, float* __restrict__ p2)
{
    __shared__ float sred[4][256], qred[4][256];
    const int b = blockIdx.x, lc = blockIdx.y;
    const int cq = threadIdx.x & 63, rg = threadIdx.x >> 6;
    const int d0 = cq * 4;
    const size_t base = ((size_t)b * 1024 + lc * 64 + rg * 16) * 256;
    float s0 = 0, s1 = 0, s2 = 0, s3 = 0;
    float q0 = 0, q1 = 0, q2 = 0, q3 = 0;
    #pragma unroll 4
    for (int l = 0; l < 16; l++) {
        float4 v = *(const float4*)&x[base + (size_t)l * 256 + d0];
        bf16x4 bv;
        bv[0] = (bf16)v.x; bv[1] = (bf16)v.y; bv[2] = (bf16)v.z; bv[3] = (bf16)v.w;
        *(bf16x4*)&xb[base + (size_t)l * 256 + d0] = bv;
        s0 += v.x; s1 += v.y; s2 += v.z; s3 += v.w;
        q0 += v.x * v.x; q1 += v.y * v.y; q2 += v.z * v.z; q3 += v.w * v.w;
    }
    sred[rg][d0] = s0; sred[rg][d0 + 1] = s1; sred[rg][d0 + 2] = s2; sred[rg][d0 + 3] = s3;
    qred[rg][d0] = q0; qred[rg][d0 + 1] = q1; qred[rg][d0 + 2] = q2; qred[rg][d0 + 3] = q3;
    __syncthreads();
    if (rg == 0) {
        #pragma unroll
        for (int k = 0; k < 4; k++) {
            const int d = d0 + k;
            float ss = sred[0][d] + sred[1][d] + sred[2][d] + sred[3][d];
            float qq = qred[0][d] + qred[1][d] + qred[2][d] + qred[3][d];
            p1[((size_t)lc * 64 + b) * 256 + d] = ss;
            p2[((size_t)lc * 64 + b) * 256 + d] = qq;
        }
    }
}

// ---------------------------------------------------------------------------
// all weight prep in ONE dispatch: 4 transposes + 4 scale/bias. 3592 blocks.
// ---------------------------------------------------------------------------
__global__ void prep_all(
    const float* __restrict__ W1, const float* __restrict__ W2,
    const float* __restrict__ W3, const float* __restrict__ W4,
    bf16* __restrict__ t1, bf16* __restrict__ t2,
    bf16* __restrict__ t3, bf16* __restrict__ t4,
    const float* b1, const float* g1, const float* be1, const float* m1, const float* v1,
    const float* b2, const float* g2, const float* be2, const float* m2, const float* v2,
    const float* b3, const float* g3, const float* be3, const float* m3, const float* v3,
    const float* b4, const float* g4, const float* be4, const float* m4, const float* v4,
    float* __restrict__ sb)
{
    const int bid = blockIdx.x, tid = threadIdx.x;
    if (bid < 512) {                       // W1: 512x256 (Wt[n][k])
        int idx = bid * 256 + tid;
        int n = idx >> 8, k = idx & 255;
        t1[idx] = (bf16)W1[k * 512 + n];
    } else if (bid < 3584) {               // W2/W3/W4: 512x512 each
        int r = bid - 512;
        int which = r >> 10;               // 1024 blocks each
        int idx = (r & 1023) * 256 + tid;
        int n = idx >> 9, k = idx & 511;
        const float* W = which == 0 ? W2 : (which == 1 ? W3 : W4);
        bf16* Wt       = which == 0 ? t2 : (which == 1 ? t3 : t4);
        Wt[idx] = (bf16)W[k * 512 + n];
    } else {                               // scale/bias: 8 blocks
        int r = bid - 3584;
        int lay = r >> 1;
        int j = (r & 1) * 256 + tid;
        const float *b, *g, *be, *m, *v;
        switch (lay) {
            case 0: b=b1; g=g1; be=be1; m=m1; v=v1; break;
            case 1: b=b2; g=g2; be=be2; m=m2; v=v2; break;
            case 2: b=b3; g=g3; be=be3; m=m3; v=v3; break;
            default:b=b4; g=g4; be=be4; m=m4; v=v4; break;
        }
        float sj = g[j] * rsqrtf(v[j] + EPS);
        sb[lay * 1024 + j]       = sj;
        sb[lay * 1024 + 512 + j] = (b[j] - m[j]) * sj + be[j];
    }
}

// ---------------------------------------------------------------------------
// GEMM: C[M,512] = relu( (A[M,K] @ Wt[512,K]^T) * s + t ), bf16 out
// (round-5 structure, unchanged: 256x256 tile, BK=64, phased counted-vmcnt
// schedule, subtiled conflict-free LDS, LDS-staged coalesced epilogue)
// ---------------------------------------------------------------------------
template<int K>
__global__ __launch_bounds__(512, 2)
void gemm_bt(const bf16* __restrict__ A, const bf16* __restrict__ Bt,
             const float* __restrict__ sc, const float* __restrict__ bi,
             bf16* __restrict__ C)
{
    constexpr int NT = K / 64;                 // 4 (K=256) or 8 (K=512)
    __shared__ __align__(16) bf16 L[2][32768]; // 2 x 64KB

    const int tid  = threadIdx.x;
    const int lane = tid & 63;
    const int wid  = tid >> 6;                 // 0..7
    const int wm   = wid >> 2;                 // 0..1
    const int wn   = wid & 3;                  // 0..3
    const int quad = lane >> 4;
    const int l16  = lane & 15;

    // XCD-aware swizzle: 512 blocks, 8 XCDs, 64 consecutive per XCD.
    const int swz = (blockIdx.x & 7) * 64 + (blockIdx.x >> 3);
    const size_t m0 = (size_t)(swz >> 1) * 256;
    const int    n0 = (swz & 1) * 256;

    // staging: this wave covers fragment blocks b0,b1 of each chunk.
    const int b0 = wid * 2, b1 = b0 + 1;
    const bf16* pA0 = &A[(m0 + (size_t)((b0 >> 3) * 128 + ((b0 >> 1) & 3) * 16 + l16)) * K + (b0 & 1) * 32 + quad * 8];
    const bf16* pA1 = &A[(m0 + (size_t)((b1 >> 3) * 128 + ((b1 >> 1) & 3) * 16 + l16)) * K + (b1 & 1) * 32 + quad * 8];
    const bf16* pB0 = &Bt[(size_t)(n0 + (b0 >> 2) * 64 + ((b0 >> 1) & 1) * 16 + l16) * K + (b0 & 1) * 32 + quad * 8];
    const bf16* pB1 = &Bt[(size_t)(n0 + (b1 >> 2) * 64 + ((b1 >> 1) & 1) * 16 + l16) * K + (b1 & 1) * 32 + quad * 8];

    f32x4  acc[8][4] = {};
    bf16x8 aF[4][2], bF0[2][2], bF1[2][2];

    auto STAGE_A = [&](int kt, int ih, int buf) {
        load_lds16(pA0 + (size_t)ih * 64 * K + kt * 64, &L[buf][ih * 8192 + b0 * 512]);
        load_lds16(pA1 + (size_t)ih * 64 * K + kt * 64, &L[buf][ih * 8192 + b1 * 512]);
    };
    auto STAGE_B = [&](int kt, int jh, int buf) {
        load_lds16(pB0 + (size_t)jh * 32 * K + kt * 64, &L[buf][16384 + jh * 8192 + b0 * 512]);
        load_lds16(pB1 + (size_t)jh * 32 * K + kt * 64, &L[buf][16384 + jh * 8192 + b1 * 512]);
    };
    auto LOAD_A = [&](int cur, int ih) {
        #pragma unroll
        for (int il = 0; il < 4; il++)
            #pragma unroll
            for (int ks = 0; ks < 2; ks++)
                aF[il][ks] = *(const bf16x8*)&L[cur][ih * 8192 + (wm * 8 + il * 2 + ks) * 512 + lane * 8];
    };
    auto LOAD_B = [&](int cur, int jh, bf16x8 (&bf)[2][2]) {
        #pragma unroll
        for (int jl = 0; jl < 2; jl++)
            #pragma unroll
            for (int ks = 0; ks < 2; ks++)
                bf[jl][ks] = *(const bf16x8*)&L[cur][16384 + jh * 8192 + (wn * 4 + jl * 2 + ks) * 512 + lane * 8];
    };
    auto MFMA16 = [&](int ih, int jh, bf16x8 (&bf)[2][2]) {
        __builtin_amdgcn_s_setprio(1);
        #pragma unroll
        for (int ks = 0; ks < 2; ks++)
            #pragma unroll
            for (int il = 0; il < 4; il++)
                #pragma unroll
                for (int jl = 0; jl < 2; jl++)
                    acc[ih * 4 + il][jh * 2 + jl] = __builtin_amdgcn_mfma_f32_16x16x32_bf16(
                        aF[il][ks], bf[jl][ks], acc[ih * 4 + il][jh * 2 + jl], 0, 0, 0);
        __builtin_amdgcn_s_setprio(0);
    };

    // prologue: stage tile 0 (chunks A0,B0,B1,A1), validate A0,B0.
    STAGE_A(0, 0, 0); STAGE_B(0, 0, 0); STAGE_B(0, 1, 0); STAGE_A(0, 1, 0);
    asm volatile("s_waitcnt vmcnt(4)" ::: "memory");
    asm volatile("s_barrier" ::: "memory");

    for (int t = 0; t < NT; ++t) {
        const int cur = t & 1, nxt = cur ^ 1;
        const bool last = (t == NT - 1);
        // ---- phase 0: reads A0,B0 (validated prev ph3) ; MFMA(0,0)
        LOAD_A(cur, 0);
        LOAD_B(cur, 0, bF0);
        if (!last) {
            STAGE_A(t + 1, 0, nxt);
            asm volatile("s_waitcnt vmcnt(4)" ::: "memory");   // validates t:B1
        } else {
            asm volatile("s_waitcnt vmcnt(2)" ::: "memory");   // validates t:B1
        }
        asm volatile("s_barrier" ::: "memory");
        asm volatile("s_waitcnt lgkmcnt(0)" ::: "memory");
        MFMA16(0, 0, bF0);
        // ---- phase 1: reads B1 (validated ph0) ; MFMA(0,1)
        LOAD_B(cur, 1, bF1);
        if (!last) {
            STAGE_B(t + 1, 0, nxt);
            asm volatile("s_waitcnt vmcnt(4)" ::: "memory");   // validates t:A1
        } else {
            asm volatile("s_waitcnt vmcnt(0)" ::: "memory");   // validates t:A1
        }
        asm volatile("s_barrier" ::: "memory");
        asm volatile("s_waitcnt lgkmcnt(0)" ::: "memory");
        MFMA16(0, 1, bF1);
        // ---- phase 2: reads A1 (validated ph1) ; no barrier needed
        LOAD_A(cur, 1);
        if (!last) STAGE_B(t + 1, 1, nxt);
        asm volatile("s_waitcnt lgkmcnt(0)" ::: "memory");
        MFMA16(1, 0, bF0);
        // ---- phase 3: no reads ; validate t+1:A0,B0 for next ph0
        if (!last) {
            STAGE_A(t + 1, 1, nxt);
            asm volatile("s_waitcnt vmcnt(4)" ::: "memory");   // validates t+1:A0,B0
            asm volatile("s_barrier" ::: "memory");
        }
        MFMA16(1, 1, bF1);
    }

    // ---- epilogue: acc -> LDS (BN+relu fused) -> coalesced bf16x8 stores
    __syncthreads();                       // all waves done with K-loop LDS
    bf16* Lf = &L[0][0];                   // 65536 bf16 = full 256x256 C tile
    #pragma unroll
    for (int j = 0; j < 4; j++) {
        const int col = wn * 64 + j * 16 + l16;
        const float s = sc[n0 + col], t = bi[n0 + col];
        #pragma unroll
        for (int i = 0; i < 8; i++) {
            const int rowb = wm * 128 + i * 16 + quad * 4;
            #pragma unroll
            for (int r = 0; r < 4; r++) {
                float v = acc[i][j][r] * s + t;
                Lf[(rowb + r) * 256 + col] = (bf16)(v > 0.f ? v : 0.f);
            }
        }
    }
    __syncthreads();
    #pragma unroll
    for (int c = 0; c < 16; c++) {
        const int e = c * 4096 + tid * 8;
        const int row = e >> 8, col = e & 255;
        *(bf16x8*)&C[(m0 + row) * 512 + n0 + col] = *(const bf16x8*)&Lf[e];
    }
}

// ---------------------------------------------------------------------------
// A[N,8] = h4[N,512](bf16) @ Wa[512,8](f32)
// ---------------------------------------------------------------------------
__global__ __launch_bounds__(256)
void compute_A(const bf16* __restrict__ h, const float* __restrict__ Wa,
               float* __restrict__ A)
{
    __shared__ float WaL[512 * 8];
    const int tid = threadIdx.x;
    for (int i = tid; i < 4096; i += 256) WaL[i] = Wa[i];
    __syncthreads();
    const size_t row = (size_t)blockIdx.x * 32 + (tid >> 3);
    const int r = tid & 7;
    const bf16* hp = h + row * 512;
    float acc0 = 0.f, acc1 = 0.f;
    #pragma unroll 4
    for (int k8 = 0; k8 < 64; k8 += 2) {
        bf16x8 h0 = *(const bf16x8*)&hp[k8 * 8];
        bf16x8 h1 = *(const bf16x8*)&hp[k8 * 8 + 8];
        #pragma unroll
        for (int j = 0; j < 8; j++) {
            acc0 += (float)h0[j] * WaL[(k8 * 8 + j) * 8 + r];
            acc1 += (float)h1[j] * WaL[(k8 * 8 + 8 + j) * 8 + r];
        }
    }
    A[row * 8 + r] = acc0 + acc1;
}

// ---------------------------------------------------------------------------
// per-segment softmax over L (8 cols) + penalty. 1024 threads.
// ---------------------------------------------------------------------------
__global__ __launch_bounds__(1024)
void seg_softmax(const float* __restrict__ A, float* __restrict__ Asg,
                 float* __restrict__ pen)
{
    __shared__ float AsL[8192];
    __shared__ float red[1024];
    __shared__ float amax[8], asum[8];
    const int b = blockIdx.x, tid = threadIdx.x;
    const float* Ab = A + (size_t)b * 8192;
    for (int i = tid * 4; i < 8192; i += 4096)
        *(float4*)&AsL[i] = *(const float4*)&Ab[i];
    __syncthreads();
    const int r = tid & 7, chunk = tid >> 3;      // 128 chunks x 8 rows
    float pm = -1e30f;
    for (int l = chunk * 8; l < chunk * 8 + 8; l++) pm = fmaxf(pm, AsL[l * 8 + r]);
    red[tid] = pm;
    __syncthreads();
    if (tid < 512) red[tid] = fmaxf(red[tid], red[tid + 512]); __syncthreads();
    if (tid < 256) red[tid] = fmaxf(red[tid], red[tid + 256]); __syncthreads();
    if (tid < 128) red[tid] = fmaxf(red[tid], red[tid + 128]); __syncthreads();
    if (tid <  64) red[tid] = fmaxf(red[tid], red[tid +  64]); __syncthreads();
    if (tid <  32) red[tid] = fmaxf(red[tid], red[tid +  32]); __syncthreads();
    if (tid <  16) red[tid] = fmaxf(red[tid], red[tid +  16]); __syncthreads();
    if (tid <   8) amax[tid] = fmaxf(red[tid], red[tid + 8]);  __syncthreads();
    const float mr = amax[r];
    float ps = 0.f;
    for (int l = chunk * 8; l < chunk * 8 + 8; l++) {
        float e = expf(AsL[l * 8 + r] - mr);
        AsL[l * 8 + r] = e;
        ps += e;
    }
    red[tid] = ps;
    __syncthreads();
    if (tid < 512) red[tid] += red[tid + 512]; __syncthreads();
    if (tid < 256) red[tid] += red[tid + 256]; __syncthreads();
    if (tid < 128) red[tid] += red[tid + 128]; __syncthreads();
    if (tid <  64) red[tid] += red[tid +  64]; __syncthreads();
    if (tid <  32) red[tid] += red[tid +  32]; __syncthreads();
    if (tid <  16) red[tid] += red[tid +  16]; __syncthreads();
    if (tid <   8) asum[tid] = red[tid] + red[tid + 8];        __syncthreads();
    const float inv = 1.f / asum[r];
    for (int l = chunk * 8; l < chunk * 8 + 8; l++) AsL[l * 8 + r] *= inv;
    __syncthreads();
    for (int i = tid * 4; i < 8192; i += 4096)
        *(float4*)&Asg[(size_t)b * 8192 + i] = *(const float4*)&AsL[i];
    __syncthreads();
    // penalty: 64 (rr,ss) pairs x 16 l-chunks of 64
    {
        const int p = tid & 63, ch = tid >> 6;
        const int rr = p >> 3, ss = p & 7;
        float dot = 0.f;
        for (int l = ch * 64; l < ch * 64 + 64; l++)
            dot += AsL[l * 8 + rr] * AsL[l * 8 + ss];
        red[tid] = dot;
    }
    __syncthreads();
    if (tid < 512) red[tid] += red[tid + 512]; __syncthreads();
    if (tid < 256) red[tid] += red[tid + 256]; __syncthreads();
    if (tid < 128) red[tid] += red[tid + 128]; __syncthreads();
    if (tid < 64) {
        float d = red[tid] + red[tid + 64] - 1.f;
        red[tid] = d * d;
    }
    __syncthreads();
    if (tid == 0) {
        float s = 0.f;
        for (int i = 0; i < 64; i++) s += red[i];
        atomicAdd(pen, s);
    }
}

// ---------------------------------------------------------------------------
// pooled partials: grid (64 b, 8 lc of 128 rows), 256 thr.
// v2: bf16x8 h loads (16B/lane coalesced, was 2B at stride 1KB!).
// thread = (colgroup of 8, rowgroup of 32); As rows in LDS (broadcast);
// acc[8][8] fully unrolled (compile-time indexed); 4-way LDS reduce.
// pp layout unchanged [8][64][8r][512] -> head1 untouched.
// ---------------------------------------------------------------------------
__global__ __launch_bounds__(256)
void pooled_k(const float* __restrict__ Asg, const bf16* __restrict__ h,
              float* __restrict__ pp)
{
    __shared__ float AsL[128 * 8];    // 4 KB: As rows for this lc
    __shared__ float red[256 * 8];    // 8 KB: cross-rowgroup reduce
    const int b = blockIdx.x, lc = blockIdx.y;
    const int tid = threadIdx.x;
    const int cg = tid & 63;          // col group: cols cg*8..+7 (512 cols)
    const int lg = tid >> 6;          // row group: 32 rows each

    *(float4*)&AsL[tid * 4] = *(const float4*)&Asg[(size_t)b * 8192 + lc * 1024 + tid * 4];
    __syncthreads();

    float acc[8][8] = {};
    const bf16* hb = h + ((size_t)b * 1024 + lc * 128 + lg * 32) * 512 + cg * 8;
    #pragma unroll 2
    for (int l = 0; l < 32; l++) {
        bf16x8 hv = *(const bf16x8*)&hb[(size_t)l * 512];
        float hf[8];
        #pragma unroll
        for (int k = 0; k < 8; k++) hf[k] = (float)hv[k];
        const float* ar = &AsL[(lg * 32 + l) * 8];
        #pragma unroll
        for (int r = 0; r < 8; r++)
            #pragma unroll
            for (int k = 0; k < 8; k++)
                acc[r][k] += ar[r] * hf[k];
    }

    float* pb = pp + ((size_t)lc * 64 + b) * 4096;
    #pragma unroll
    for (int r = 0; r < 8; r++) {
        __syncthreads();
        *(float4*)&red[tid * 8]     = *(float4*)&acc[r][0];
        *(float4*)&red[tid * 8 + 4] = *(float4*)&acc[r][4];
        __syncthreads();
        if (tid < 64) {
            #pragma unroll
            for (int k = 0; k < 8; k++) {
                float v = red[tid * 8 + k] + red[(tid + 64) * 8 + k]
                        + red[(tid + 128) * 8 + k] + red[(tid + 192) * 8 + k];
                pb[r * 512 + tid * 8 + k] = v;
            }
        }
    }
}

// ---------------------------------------------------------------------------
// head pass 1: z[b][c] += feat-chunk @ Wo1-slice. grid (64, 9)
// kc==8 computes mean/std inline from the convert_stats partials.
// ---------------------------------------------------------------------------
__global__ __launch_bounds__(128)
void head1(const float* __restrict__ pp, const float* __restrict__ p1,
           const float* __restrict__ p2, const float* __restrict__ Wo1,
           float* __restrict__ zbuf)
{
    __shared__ float f[512];
    const int b = blockIdx.x, kc = blockIdx.y, tid = threadIdx.x;
    if (kc < 8) {
        for (int j = tid; j < 512; j += 128) {
            const size_t i = (size_t)kc * 512 + j;
            float s = 0.f;
            #pragma unroll
            for (int lc = 0; lc < 8; lc++)
                s += pp[((size_t)lc * 64 + b) * 4096 + i];
            f[j] = s;
        }
    } else {
        for (int j = tid; j < 256; j += 128) {
            float s = 0.f, s2 = 0.f;
            #pragma unroll
            for (int lc = 0; lc < 16; lc++) {
                s  += p1[((size_t)lc * 64 + b) * 256 + j];
                s2 += p2[((size_t)lc * 64 + b) * 256 + j];
            }
            float m = s * (1.f / 1024.f);
            float var = (s2 - s * m) * (1.f / 1023.f);
            f[j]       = m;
            f[256 + j] = sqrtf(fmaxf(var, 0.f));
        }
    }
    __syncthreads();
    const float* Wp = Wo1 + (size_t)kc * 512 * 128 + tid;
    float z = 0.f;
    #pragma unroll 8
    for (int j = 0; j < 512; j++) z += f[j] * Wp[(size_t)j * 128];
    atomicAdd(&zbuf[b * 128 + tid], z);
}

// ---------------------------------------------------------------------------
// head pass 2: BN+relu -> @ Wo2 -> log_softmax; b==0 writes penalty
// ---------------------------------------------------------------------------
__global__ __launch_bounds__(128)
void head2(const float* __restrict__ zbuf, const float* __restrict__ bo1,
           const float* __restrict__ go, const float* __restrict__ beo,
           const float* __restrict__ mo, const float* __restrict__ vo,
           const float* __restrict__ Wo2, const float* __restrict__ bo2,
           const float* __restrict__ pen, float* __restrict__ out)
{
    __shared__ float o[128];
    __shared__ float lg[4];
    const int b = blockIdx.x, tid = threadIdx.x;
    float z = zbuf[b * 128 + tid];
    float s = go[tid] * rsqrtf(vo[tid] + EPS);
    float t = (bo1[tid] - mo[tid]) * s + beo[tid];
    float ov = z * s + t;
    o[tid] = ov > 0.f ? ov : 0.f;
    __syncthreads();
    if (tid < 4) {
        float acc = bo2[tid];
        for (int j = 0; j < 128; j++) acc += o[j] * Wo2[j * 4 + tid];
        lg[tid] = acc;
    }
    __syncthreads();
    if (tid == 0) {
        float m = fmaxf(fmaxf(lg[0], lg[1]), fmaxf(lg[2], lg[3]));
        float sum = 0.f;
        for (int k = 0; k < 4; k++) sum += expf(lg[k] - m);
        float lse = m + logf(sum);
        for (int k = 0; k < 4; k++) out[b * 4 + k] = lg[k] - lse;
        if (b == 0) out[256] = pen[0];
    }
}

// ---------------------------------------------------------------------------
extern "C" void kernel_launch(void* const* d_in, const int* in_sizes, int n_in,
                              void* d_out, int out_size, void* d_ws, size_t ws_size,
                              hipStream_t stream)
{
    const float* x   = (const float*)d_in[0];
    const float* Wa  = (const float*)d_in[2];
    const float* Wo1 = (const float*)d_in[3];
    const float* bo1 = (const float*)d_in[4];
    const float* go  = (const float*)d_in[5];
    const float* beo = (const float*)d_in[6];
    const float* mo  = (const float*)d_in[7];
    const float* vo  = (const float*)d_in[8];
    const float* Wo2 = (const float*)d_in[9];
    const float* bo2 = (const float*)d_in[10];
    const float *W[4], *bb[4], *gg[4], *be[4], *mm[4], *vv[4];
    for (int l = 0; l < 4; l++) {
        W[l]  = (const float*)d_in[11 + 6 * l + 0];
        bb[l] = (const float*)d_in[11 + 6 * l + 1];
        gg[l] = (const float*)d_in[11 + 6 * l + 2];
        be[l] = (const float*)d_in[11 + 6 * l + 3];
        mm[l] = (const float*)d_in[11 + 6 * l + 4];
        vv[l] = (const float*)d_in[11 + 6 * l + 5];
    }

    char* w = (char*)d_ws;
    bf16* xb  = (bf16*)w;  w += (size_t)65536 * 256 * 2;   // 32 MB
    bf16* hA  = (bf16*)w;  w += (size_t)65536 * 512 * 2;   // 64 MB
    bf16* hB  = (bf16*)w;  w += (size_t)65536 * 512 * 2;   // 64 MB
    bf16* w1t = (bf16*)w;  w += (size_t)512 * 256 * 2;
    bf16* w2t = (bf16*)w;  w += (size_t)512 * 512 * 2;
    bf16* w3t = (bf16*)w;  w += (size_t)512 * 512 * 2;
    bf16* w4t = (bf16*)w;  w += (size_t)512 * 512 * 2;
    float* sb = (float*)w; w += (size_t)4 * 1024 * 4;      // [layer][s|t][512]
    float* Ab = (float*)w; w += (size_t)65536 * 8 * 4;
    float* As = (float*)w; w += (size_t)65536 * 8 * 4;
    float* pp = (float*)w; w += (size_t)8 * 64 * 4096 * 4; // pooled partials
    float* p1 = (float*)w; w += (size_t)16 * 64 * 256 * 4;
    float* p2 = (float*)w; w += (size_t)16 * 64 * 256 * 4;
    float* zbuf = (float*)w; w += (size_t)64 * 128 * 4;
    float* pen = (float*)w;

    hipMemsetAsync(zbuf, 0, (64 * 128 + 1) * sizeof(float), stream); // zbuf + pen

    convert_stats<<<dim3(64, 16), 256, 0, stream>>>(x, xb, p1, p2);
    prep_all<<<3592, 256, 0, stream>>>(
        W[0], W[1], W[2], W[3], w1t, w2t, w3t, w4t,
        bb[0], gg[0], be[0], mm[0], vv[0],
        bb[1], gg[1], be[1], mm[1], vv[1],
        bb[2], gg[2], be[2], mm[2], vv[2],
        bb[3], gg[3], be[3], mm[3], vv[3], sb);

    gemm_bt<256><<<512, 512, 0, stream>>>(xb, w1t, sb + 0,    sb + 512,  hA);
    gemm_bt<512><<<512, 512, 0, stream>>>(hA, w2t, sb + 1024, sb + 1536, hB);
    gemm_bt<512><<<512, 512, 0, stream>>>(hB, w3t, sb + 2048, sb + 2560, hA);
    gemm_bt<512><<<512, 512, 0, stream>>>(hA, w4t, sb + 3072, sb + 3584, hB);

    compute_A<<<2048, 256, 0, stream>>>(hB, Wa, Ab);
    seg_softmax<<<64, 1024, 0, stream>>>(Ab, As, pen);
    pooled_k<<<dim3(64, 8), 256, 0, stream>>>(As, hB, pp);
    head1<<<dim3(64, 9), 128, 0, stream>>>(pp, p1, p2, Wo1, zbuf);
    head2<<<64, 128, 0, stream>>>(zbuf, bo1, go, beo, mo, vo, Wo2, bo2,
                                  pen, (float*)d_out);
}